// Round 1
// baseline (628.706 us; speedup 1.0000x reference)
//
#include <hip/hip_runtime.h>
#include <math.h>

// Gen2AssocModel forward. T=512, B=64, N=32, HID=1024, SEQ_WIDTH=64.
// Pipeline:
//   prep:  W1eff = W_in @ [Wk1|Wv1|Wq1]  (65x96), b1eff, and const kvq2 row
//          for spike-free rows (relu(b_mid) @ [Wk2|Wv2|Wq2] + b2).
//   kvq1:  (32768x65) @ (65x96) -> k1,v1,q1 (q sigmoided).
//   scan1: per-(b,i,j) private membrane over t=0..511 -> spike bitmasks.
//   mid:   per row: if no spikes -> const kvq2 row; else sparse-accumulate
//          h2 = relu(sum q1[i]*W_mid[i*32+j,:] + b_mid) then (1024)@(1024x96).
//   scan2: same as scan1 on kvq2 -> masks2.
//   out:   y = sigmoid(sum q2[i]*W_out[i*32+j,:] + b_out), skip zero rows.
// Workspace (~33.6 MB): W1eff/b1eff/const2 | kvq1 | kvq2 | masks1 | masks2.

#define T_STEPS 512
#define BATCH   64
#define NN      32
#define HID     1024
#define INW     65
#define OUTW    64
#define ROWS    (T_STEPS * BATCH)   // 32768
#define KVQ     96

__device__ __forceinline__ float sigmoidf_(float x) { return 1.0f / (1.0f + expf(-x)); }

// ---------------------------------------------------------------- prep
__global__ void prep_kernel(const float* __restrict__ W_in, const float* __restrict__ b_in,
                            const float* __restrict__ Wk1, const float* __restrict__ bk1,
                            const float* __restrict__ Wv1, const float* __restrict__ bv1,
                            const float* __restrict__ Wq1, const float* __restrict__ bq1,
                            const float* __restrict__ b_mid,
                            const float* __restrict__ Wk2, const float* __restrict__ bk2,
                            const float* __restrict__ Wv2, const float* __restrict__ bv2,
                            const float* __restrict__ Wq2, const float* __restrict__ bq2,
                            float* __restrict__ W1eff, float* __restrict__ b1eff,
                            float* __restrict__ const2)
{
    const int n = blockIdx.x;          // 0..95
    const int sel = n >> 5, nn = n & 31;
    const float* W1 = sel == 0 ? Wk1 : sel == 1 ? Wv1 : Wq1;
    const float* b1 = sel == 0 ? bk1 : sel == 1 ? bv1 : bq1;
    const float* W2 = sel == 0 ? Wk2 : sel == 1 ? Wv2 : Wq2;
    const float* b2 = sel == 0 ? bk2 : sel == 1 ? bv2 : bq2;
    const int m = threadIdx.x;         // 128 threads
    if (m < INW) {
        float acc = 0.f;
        for (int h = 0; h < HID; ++h) acc = fmaf(W_in[m * HID + h], W1[h * NN + nn], acc);
        W1eff[m * KVQ + n] = acc;
    } else if (m == INW) {
        float acc = b1[nn];
        for (int h = 0; h < HID; ++h) acc = fmaf(b_in[h], W1[h * NN + nn], acc);
        b1eff[n] = acc;
    } else if (m == INW + 1) {
        // kvq2 row for a spike-free out1 row: h2 = relu(b_mid)
        float acc = b2[nn];
        for (int c = 0; c < HID; ++c) acc = fmaf(fmaxf(b_mid[c], 0.f), W2[c * NN + nn], acc);
        if (sel == 2) acc = sigmoidf_(acc);
        const2[n] = acc;
    }
}

// ---------------------------------------------------------------- kvq1
__global__ void kvq1_kernel(const float* __restrict__ x, const float* __restrict__ W1eff,
                            const float* __restrict__ b1eff, float* __restrict__ kvq1)
{
    const int row = blockIdx.x;        // 0..32767  (t*64+b)
    const int tid = threadIdx.x;       // 128 threads
    __shared__ float xs[INW];
    if (tid < INW) xs[tid] = x[row * INW + tid];
    __syncthreads();
    if (tid < KVQ) {
        float acc = b1eff[tid];
        #pragma unroll
        for (int m = 0; m < INW; ++m) acc = fmaf(xs[m], W1eff[m * KVQ + tid], acc);
        if (tid >= 2 * NN) acc = sigmoidf_(acc);   // q gate
        kvq1[row * KVQ + tid] = acc;
    }
}

// ---------------------------------------------------------------- scan
// grid: 256 blocks = b*4 + iq ; 256 threads: i = iq*8 + (tid>>5), j = tid&31.
// Each thread owns mem[b,i,j] in a register for all 512 steps.
// Wave lanes 0..31 -> one i-row (all j), lanes 32..63 -> next i-row, so the
// 64-bit ballot's low/high halves are the two rows' spike masks.
__global__ void scan_kernel(const float* __restrict__ kvq, unsigned int* __restrict__ masks)
{
    const int blk = blockIdx.x;
    const int b = blk >> 2, iq = blk & 3;
    const int tid = threadIdx.x;
    const int i = iq * 8 + (tid >> 5);
    const int j = tid & 31;
    const float* base = kvq + b * KVQ;
    const int lane = tid & 63;
    unsigned int* mrow = masks + b * NN + i;   // + t*2048 each step
    float mem = 0.f;
    #pragma unroll 4
    for (int t = 0; t < T_STEPS; ++t) {
        const float* r = base + t * (BATCH * KVQ);
        const float k = r[i];
        const float v = r[NN + j];
        mem = fmaf(0.9f, mem, k * v);
        const bool s = mem > 1.0f;
        if (s) mem -= 1.0f;
        const unsigned long long m = __ballot(s);
        // unconditional writes: ws is poisoned, downstream reads every mask
        if (lane == 0)  mrow[t * (BATCH * NN)] = (unsigned int)m;
        if (lane == 32) mrow[t * (BATCH * NN)] = (unsigned int)(m >> 32);
    }
}

// ---------------------------------------------------------------- mid (out1 @ W_mid -> relu -> kvq2)
__global__ void mid_kernel(const unsigned int* __restrict__ masks1, const float* __restrict__ kvq1,
                           const float* __restrict__ W_mid, const float* __restrict__ b_mid,
                           const float* __restrict__ Wk2, const float* __restrict__ bk2,
                           const float* __restrict__ Wv2, const float* __restrict__ bv2,
                           const float* __restrict__ Wq2, const float* __restrict__ bq2,
                           const float* __restrict__ const2, float* __restrict__ kvq2)
{
    const int row = blockIdx.x;        // 32768
    const int tid = threadIdx.x;       // 128
    __shared__ unsigned int ms[NN];
    if (tid < NN) ms[tid] = masks1[row * NN + tid];
    __syncthreads();
    unsigned int any = 0;
    #pragma unroll
    for (int i = 0; i < NN; ++i) any |= ms[i];   // LDS broadcast, uniform
    if (!any) {
        if (tid < KVQ) kvq2[row * KVQ + tid] = const2[tid];
        return;
    }
    // sparse path: reconstruct h2 from spike bits
    __shared__ float h2[HID];
    for (int c = tid; c < HID; c += 128) h2[c] = b_mid[c];
    for (int i = 0; i < NN; ++i) {
        unsigned int m = ms[i];
        if (!m) continue;
        const float qv = kvq1[row * KVQ + 2 * NN + i];
        while (m) {
            const int j = __ffs(m) - 1; m &= m - 1;
            const float* wrow = W_mid + (i * NN + j) * HID;
            for (int c = tid; c < HID; c += 128) h2[c] = fmaf(qv, wrow[c], h2[c]);
        }
    }
    __syncthreads();
    for (int c = tid; c < HID; c += 128) h2[c] = fmaxf(h2[c], 0.f);
    __syncthreads();
    if (tid < KVQ) {
        const int sel = tid >> 5, nn = tid & 31;
        const float* W2 = sel == 0 ? Wk2 : sel == 1 ? Wv2 : Wq2;
        float acc = (sel == 0 ? bk2 : sel == 1 ? bv2 : bq2)[nn];
        for (int c = 0; c < HID; ++c) acc = fmaf(h2[c], W2[c * NN + nn], acc);
        if (sel == 2) acc = sigmoidf_(acc);
        kvq2[row * KVQ + tid] = acc;
    }
}

// ---------------------------------------------------------------- out (out2 @ W_out -> sigmoid)
__global__ void out_kernel(const unsigned int* __restrict__ masks2, const float* __restrict__ kvq2,
                           const float* __restrict__ W_out, const float* __restrict__ b_out,
                           float* __restrict__ y)
{
    const int row = blockIdx.x;        // 32768
    const int tid = threadIdx.x;       // 64
    __shared__ unsigned int ms[NN];
    if (tid < NN) ms[tid] = masks2[row * NN + tid];
    __syncthreads();
    float acc = b_out[tid];
    for (int i = 0; i < NN; ++i) {
        unsigned int m = ms[i];
        if (!m) continue;
        const float qv = kvq2[row * KVQ + 2 * NN + i];
        while (m) {
            const int j = __ffs(m) - 1; m &= m - 1;
            acc = fmaf(qv, W_out[(i * NN + j) * OUTW + tid], acc);
        }
    }
    y[row * OUTW + tid] = sigmoidf_(acc);
}

// ---------------------------------------------------------------- launch
extern "C" void kernel_launch(void* const* d_in, const int* in_sizes, int n_in,
                              void* d_out, int out_size, void* d_ws, size_t ws_size,
                              hipStream_t stream)
{
    const float* x     = (const float*)d_in[0];
    const float* W_in  = (const float*)d_in[1];
    const float* b_in  = (const float*)d_in[2];
    const float* Wk1   = (const float*)d_in[3];
    const float* bk1   = (const float*)d_in[4];
    const float* Wv1   = (const float*)d_in[5];
    const float* bv1   = (const float*)d_in[6];
    const float* Wq1   = (const float*)d_in[7];
    const float* bq1   = (const float*)d_in[8];
    const float* W_mid = (const float*)d_in[9];
    const float* b_mid = (const float*)d_in[10];
    const float* Wk2   = (const float*)d_in[11];
    const float* bk2   = (const float*)d_in[12];
    const float* Wv2   = (const float*)d_in[13];
    const float* bv2   = (const float*)d_in[14];
    const float* Wq2   = (const float*)d_in[15];
    const float* bq2   = (const float*)d_in[16];
    const float* W_out = (const float*)d_in[17];
    const float* b_out = (const float*)d_in[18];
    float* y = (float*)d_out;

    float* ws = (float*)d_ws;
    float* W1eff  = ws;                                // 65*96 = 6240
    float* b1eff  = ws + 6240;                         // 96
    float* const2 = ws + 6336;                         // 96
    float* kvq1   = ws + 8192;                         // 32768*96 = 3,145,728
    float* kvq2   = ws + 8192 + 3145728;               // 3,145,728
    unsigned int* masks1 = (unsigned int*)(ws + 8192 + 2 * 3145728);       // 1,048,576
    unsigned int* masks2 = (unsigned int*)(ws + 8192 + 2 * 3145728 + 1048576);
    // total: (8192 + 2*3145728 + 2*1048576) * 4 B ≈ 33.6 MB <= ws_size (assumed)

    prep_kernel<<<KVQ, 128, 0, stream>>>(W_in, b_in, Wk1, bk1, Wv1, bv1, Wq1, bq1,
                                         b_mid, Wk2, bk2, Wv2, bv2, Wq2, bq2,
                                         W1eff, b1eff, const2);
    kvq1_kernel<<<ROWS, 128, 0, stream>>>(x, W1eff, b1eff, kvq1);
    scan_kernel<<<BATCH * 4, 256, 0, stream>>>(kvq1, masks1);
    mid_kernel<<<ROWS, 128, 0, stream>>>(masks1, kvq1, W_mid, b_mid,
                                         Wk2, bk2, Wv2, bv2, Wq2, bq2, const2, kvq2);
    scan_kernel<<<BATCH * 4, 256, 0, stream>>>(kvq2, masks2);
    out_kernel<<<ROWS, 64, 0, stream>>>(masks2, kvq2, W_out, b_out, y);
}

// Round 2
// 279.791 us; speedup vs baseline: 2.2471x; 2.2471x over previous
//
#include <hip/hip_runtime.h>
#include <math.h>

// Gen2AssocModel forward. T=512, B=64, N=32, HID=1024, SEQ_WIDTH=64.
//   prep:  W1eff = W_in @ [Wk1|Wv1|Wq1] (65x96), b1eff, const2 (kvq2 row for
//          spike-free out1 rows). Wave-per-output, coalesced, shuffle-reduce.
//   kvq1:  (32768x65)@(65x96) -> k1,v1,q1 (q sigmoided), b-major [b][t][96].
//   scan:  per-(b,i,j) private membrane over t; LDS double-buffered chunk
//          staging (128 steps); spike bitmasks via wave ballot.
//   mid:   spike-free rows -> const2; else sparse accumulate + dense 1024x96.
//   out:   y = sigmoid(sparse accumulate + b_out).
// Workspace (~33.6 MB): W1eff/b1eff/const2 | kvq1 | kvq2 | masks1 | masks2.

#define T_STEPS 512
#define BATCH   64
#define NN      32
#define HID     1024
#define INW     65
#define OUTW    64
#define ROWS    (T_STEPS * BATCH)   // 32768
#define KVQ     96
#define CHUNK   128                 // scan staging chunk (T_STEPS/CHUNK = 4)

__device__ __forceinline__ float sigmoidf_(float x) { return 1.0f / (1.0f + expf(-x)); }

// ---------------------------------------------------------------- prep
// grid 96 (one per output col n), block 256 (4 waves).
__global__ __launch_bounds__(256) void prep_kernel(
    const float* __restrict__ W_in, const float* __restrict__ b_in,
    const float* __restrict__ Wk1, const float* __restrict__ bk1,
    const float* __restrict__ Wv1, const float* __restrict__ bv1,
    const float* __restrict__ Wq1, const float* __restrict__ bq1,
    const float* __restrict__ b_mid,
    const float* __restrict__ Wk2, const float* __restrict__ bk2,
    const float* __restrict__ Wv2, const float* __restrict__ bv2,
    const float* __restrict__ Wq2, const float* __restrict__ bq2,
    float* __restrict__ W1eff, float* __restrict__ b1eff,
    float* __restrict__ const2)
{
    const int n = blockIdx.x;                 // 0..95
    const int sel = n >> 5, nn = n & 31;
    const float* W1 = sel == 0 ? Wk1 : sel == 1 ? Wv1 : Wq1;
    const float* b1 = sel == 0 ? bk1 : sel == 1 ? bv1 : bq1;
    const float* W2 = sel == 0 ? Wk2 : sel == 1 ? Wv2 : Wq2;
    const float* b2 = sel == 0 ? bk2 : sel == 1 ? bv2 : bq2;
    const int tid = threadIdx.x;
    __shared__ float W1col[HID], W2col[HID];
    for (int h = tid; h < HID; h += 256) {
        W1col[h] = W1[h * NN + nn];
        W2col[h] = W2[h * NN + nn];
    }
    __syncthreads();
    const int w = tid >> 6, l = tid & 63;
    for (int m = w; m < INW; m += 4) {
        float p = 0.f;
        #pragma unroll
        for (int i = 0; i < HID / 64; ++i)
            p = fmaf(W_in[m * HID + 64 * i + l], W1col[64 * i + l], p);
        #pragma unroll
        for (int off = 32; off; off >>= 1) p += __shfl_down(p, off);
        if (l == 0) W1eff[m * KVQ + n] = p;
    }
    if (w == 0) {
        float p = 0.f;
        #pragma unroll
        for (int i = 0; i < HID / 64; ++i)
            p = fmaf(b_in[64 * i + l], W1col[64 * i + l], p);
        #pragma unroll
        for (int off = 32; off; off >>= 1) p += __shfl_down(p, off);
        if (l == 0) b1eff[n] = p + b1[nn];
    }
    if (w == 1) {
        float p = 0.f;
        #pragma unroll
        for (int i = 0; i < HID / 64; ++i)
            p = fmaf(fmaxf(b_mid[64 * i + l], 0.f), W2col[64 * i + l], p);
        #pragma unroll
        for (int off = 32; off; off >>= 1) p += __shfl_down(p, off);
        if (l == 0) {
            float acc = p + b2[nn];
            const2[n] = (sel == 2) ? sigmoidf_(acc) : acc;
        }
    }
}

// ---------------------------------------------------------------- kvq1
// grid 2048, block 256; 16 rows per block; W1eff staged in LDS.
// Output b-major: kvq1[(b*T + t)*96 + col].
__global__ __launch_bounds__(256) void kvq1_kernel(
    const float* __restrict__ x, const float* __restrict__ W1eff,
    const float* __restrict__ b1eff, float* __restrict__ kvq1)
{
    const int tid = threadIdx.x;
    const int r0 = blockIdx.x * 16;
    __shared__ float Ws[INW * KVQ];    // 24.4 KB
    __shared__ float xs[16 * INW];     // 4.1 KB
    __shared__ float bs[KVQ];
    for (int i = tid; i < INW * KVQ; i += 256) Ws[i] = W1eff[i];
    for (int i = tid; i < 16 * INW; i += 256) xs[i] = x[r0 * INW + i];
    if (tid < KVQ) bs[tid] = b1eff[tid];
    __syncthreads();
    const int rr = tid >> 4;           // 0..15
    const int c0 = (tid & 15) * 6;     // cols [c0, c0+6)
    float acc[6];
    #pragma unroll
    for (int k = 0; k < 6; ++k) acc[k] = bs[c0 + k];
    #pragma unroll 5
    for (int m = 0; m < INW; ++m) {
        const float xv = xs[rr * INW + m];
        #pragma unroll
        for (int k = 0; k < 6; ++k)
            acc[k] = fmaf(xv, Ws[m * KVQ + c0 + k], acc[k]);
    }
    const int g = r0 + rr;             // = t*64 + b
    const int t = g >> 6, b = g & 63;
    float* o = kvq1 + (b * T_STEPS + t) * KVQ;
    #pragma unroll
    for (int k = 0; k < 6; ++k) {
        const int col = c0 + k;
        o[col] = (col >= 2 * NN) ? sigmoidf_(acc[k]) : acc[k];
    }
}

// ---------------------------------------------------------------- scan
// grid 256 = b*4+iq, block 256 (4 waves). i = iq*8 + (tid>>5), j = tid&31.
// kvq is b-major [b][t][96]. Stages CHUNK steps x 40 floats (k:8, v:32) into
// double-buffered LDS; masks staged in LDS, flushed coalesced per chunk.
__global__ __launch_bounds__(256) void scan_kernel(
    const float* __restrict__ kvq, unsigned int* __restrict__ masks)
{
    const int blk = blockIdx.x;
    const int b = blk >> 2, iq = blk & 3;
    const int tid = threadIdx.x;
    const int ksub = tid >> 5;         // 0..7
    const int j = tid & 31;
    const int lane = tid & 63;
    __shared__ float buf[2][CHUNK * 40];   // 40 KB
    __shared__ unsigned int mbuf[CHUNK * 8]; // 4 KB
    const float* base = kvq + b * T_STEPS * KVQ;

    // per-thread staging slots: l = tid + 256*r, r<5 -> (dt, seg)
    int goff[5], loff[5];
    #pragma unroll
    for (int r = 0; r < 5; ++r) {
        const int l = tid + 256 * r;
        const int dt = l / 10, s = l - 10 * dt;
        goff[r] = dt * KVQ + ((s < 2) ? (iq * 8 + 4 * s) : (2 * NN + 4 * (s - 2)));
        loff[r] = dt * 40 + ((s < 2) ? 4 * s : 8 + 4 * (s - 2));
    }
    float4 reg[5];
    #pragma unroll
    for (int r = 0; r < 5; ++r) reg[r] = *(const float4*)(base + goff[r]);
    #pragma unroll
    for (int r = 0; r < 5; ++r) *(float4*)&buf[0][loff[r]] = reg[r];
    __syncthreads();

    float mem = 0.f;
    for (int c = 0; c < T_STEPS / CHUNK; ++c) {
        const int cur = c & 1;
        if (c < T_STEPS / CHUNK - 1) {
            const float* nb = base + (c + 1) * CHUNK * KVQ;
            #pragma unroll
            for (int r = 0; r < 5; ++r) reg[r] = *(const float4*)(nb + goff[r]);
        }
        const float* Bf = buf[cur];
        #pragma unroll 8
        for (int dt = 0; dt < CHUNK; ++dt) {
            const float k = Bf[dt * 40 + ksub];
            const float v = Bf[dt * 40 + 8 + j];
            mem = fmaf(0.9f, mem, k * v);
            const bool s = mem > 1.0f;
            if (s) mem -= 1.0f;
            const unsigned long long m = __ballot(s);
            if (lane == 0)  mbuf[dt * 8 + ksub] = (unsigned int)m;
            if (lane == 32) mbuf[dt * 8 + ksub] = (unsigned int)(m >> 32);
        }
        __syncthreads();   // compute done; buf[cur^1] free; mbuf complete
        if (c < T_STEPS / CHUNK - 1) {
            #pragma unroll
            for (int r = 0; r < 5; ++r) *(float4*)&buf[cur ^ 1][loff[r]] = reg[r];
        }
        // flush masks: (t0+dt)*2048 + b*32 + iq*8 + ii
        #pragma unroll
        for (int r = 0; r < 4; ++r) {
            const int l = tid + 256 * r;
            const int dt = l >> 3, ii = l & 7;
            masks[(c * CHUNK + dt) * (BATCH * NN) + b * NN + iq * 8 + ii] =
                mbuf[dt * 8 + ii];
        }
        __syncthreads();   // staged buffer + mbuf reuse safe
    }
}

// ---------------------------------------------------------------- mid
// block row = t*64+b. Fast path (no spikes): copy const2. Sparse path:
// reconstruct h2 from spike bits, then (1024)@(1024x96).
__global__ __launch_bounds__(128) void mid_kernel(
    const unsigned int* __restrict__ masks1, const float* __restrict__ kvq1,
    const float* __restrict__ W_mid, const float* __restrict__ b_mid,
    const float* __restrict__ Wk2, const float* __restrict__ bk2,
    const float* __restrict__ Wv2, const float* __restrict__ bv2,
    const float* __restrict__ Wq2, const float* __restrict__ bq2,
    const float* __restrict__ const2, float* __restrict__ kvq2)
{
    const int row = blockIdx.x;        // t*64+b
    const int tid = threadIdx.x;       // 128
    const int t = row >> 6, b = row & 63;
    const int brow = (b * T_STEPS + t) * KVQ;
    __shared__ unsigned int ms[NN];
    if (tid < NN) ms[tid] = masks1[row * NN + tid];
    __syncthreads();
    unsigned int any = 0;
    #pragma unroll
    for (int i = 0; i < NN; ++i) any |= ms[i];
    if (!any) {
        if (tid < KVQ) kvq2[brow + tid] = const2[tid];
        return;
    }
    __shared__ float h2[HID];
    for (int c = tid; c < HID; c += 128) h2[c] = b_mid[c];
    for (int i = 0; i < NN; ++i) {
        unsigned int m = ms[i];
        if (!m) continue;
        const float qv = kvq1[brow + 2 * NN + i];
        while (m) {
            const int jj = __ffs(m) - 1; m &= m - 1;
            const float* wrow = W_mid + (i * NN + jj) * HID;
            for (int c = tid; c < HID; c += 128) h2[c] = fmaf(qv, wrow[c], h2[c]);
        }
    }
    __syncthreads();
    for (int c = tid; c < HID; c += 128) h2[c] = fmaxf(h2[c], 0.f);
    __syncthreads();
    if (tid < KVQ) {
        const int sel = tid >> 5, nn = tid & 31;
        const float* W2 = sel == 0 ? Wk2 : sel == 1 ? Wv2 : Wq2;
        float acc = (sel == 0 ? bk2 : sel == 1 ? bv2 : bq2)[nn];
        for (int c = 0; c < HID; ++c) acc = fmaf(h2[c], W2[c * NN + nn], acc);
        if (sel == 2) acc = sigmoidf_(acc);
        kvq2[brow + tid] = acc;
    }
}

// ---------------------------------------------------------------- out
__global__ __launch_bounds__(64) void out_kernel(
    const unsigned int* __restrict__ masks2, const float* __restrict__ kvq2,
    const float* __restrict__ W_out, const float* __restrict__ b_out,
    float* __restrict__ y)
{
    const int row = blockIdx.x;        // t*64+b
    const int tid = threadIdx.x;       // 64
    const int t = row >> 6, b = row & 63;
    __shared__ unsigned int ms[NN];
    if (tid < NN) ms[tid] = masks2[row * NN + tid];
    __syncthreads();
    float acc = b_out[tid];
    for (int i = 0; i < NN; ++i) {
        unsigned int m = ms[i];
        if (!m) continue;
        const float qv = kvq2[(b * T_STEPS + t) * KVQ + 2 * NN + i];
        while (m) {
            const int jj = __ffs(m) - 1; m &= m - 1;
            acc = fmaf(qv, W_out[(i * NN + jj) * OUTW + tid], acc);
        }
    }
    y[row * OUTW + tid] = sigmoidf_(acc);
}

// ---------------------------------------------------------------- launch
extern "C" void kernel_launch(void* const* d_in, const int* in_sizes, int n_in,
                              void* d_out, int out_size, void* d_ws, size_t ws_size,
                              hipStream_t stream)
{
    const float* x     = (const float*)d_in[0];
    const float* W_in  = (const float*)d_in[1];
    const float* b_in  = (const float*)d_in[2];
    const float* Wk1   = (const float*)d_in[3];
    const float* bk1   = (const float*)d_in[4];
    const float* Wv1   = (const float*)d_in[5];
    const float* bv1   = (const float*)d_in[6];
    const float* Wq1   = (const float*)d_in[7];
    const float* bq1   = (const float*)d_in[8];
    const float* W_mid = (const float*)d_in[9];
    const float* b_mid = (const float*)d_in[10];
    const float* Wk2   = (const float*)d_in[11];
    const float* bk2   = (const float*)d_in[12];
    const float* Wv2   = (const float*)d_in[13];
    const float* bv2   = (const float*)d_in[14];
    const float* Wq2   = (const float*)d_in[15];
    const float* bq2   = (const float*)d_in[16];
    const float* W_out = (const float*)d_in[17];
    const float* b_out = (const float*)d_in[18];
    float* y = (float*)d_out;

    float* ws = (float*)d_ws;
    float* W1eff  = ws;                                // 65*96 = 6240
    float* b1eff  = ws + 6240;                         // 96
    float* const2 = ws + 6336;                         // 96
    float* kvq1   = ws + 8192;                         // 32768*96, b-major
    float* kvq2   = ws + 8192 + 3145728;               // b-major
    unsigned int* masks1 = (unsigned int*)(ws + 8192 + 2 * 3145728);
    unsigned int* masks2 = (unsigned int*)(ws + 8192 + 2 * 3145728 + 1048576);

    prep_kernel<<<KVQ, 256, 0, stream>>>(W_in, b_in, Wk1, bk1, Wv1, bv1, Wq1, bq1,
                                         b_mid, Wk2, bk2, Wv2, bv2, Wq2, bq2,
                                         W1eff, b1eff, const2);
    kvq1_kernel<<<ROWS / 16, 256, 0, stream>>>(x, W1eff, b1eff, kvq1);
    scan_kernel<<<BATCH * 4, 256, 0, stream>>>(kvq1, masks1);
    mid_kernel<<<ROWS, 128, 0, stream>>>(masks1, kvq1, W_mid, b_mid,
                                         Wk2, bk2, Wv2, bv2, Wq2, bq2, const2, kvq2);
    scan_kernel<<<BATCH * 4, 256, 0, stream>>>(kvq2, masks2);
    out_kernel<<<ROWS, 64, 0, stream>>>(masks2, kvq2, W_out, b_out, y);
}

// Round 3
// 211.746 us; speedup vs baseline: 2.9692x; 1.3214x over previous
//
#include <hip/hip_runtime.h>
#include <math.h>

// Gen2AssocModel forward. T=512, B=64, N=32, HID=1024, SEQ_WIDTH=64.
//   prep:  W1eff = W_in @ [Wk1|Wv1|Wq1] (65x96), b1eff, const2 (kvq2 row for
//          spike-free out1 rows). Lane=output-col orientation, coalesced,
//          4-way K-split + LDS reduce.
//   kvq1:  (32768x65)@(65x96) -> k1,v1,q1 (q sigmoided), b-major [b][t][96].
//   scan:  per-(b,i,j) private membrane; LDS double-buffered chunk staging;
//          spike bits accumulated in registers (NO per-step ballot), LDS
//          bit-transpose per chunk -> mask words.
//   mid:   ballot fast path (no spikes) -> const2; else sparse accumulate.
//   out:   ballot fast path -> sigmoid(b_out); else sparse accumulate.
// Workspace (~33.6 MB): W1eff/b1eff/const2 | kvq1 | kvq2 | masks1 | masks2.

#define T_STEPS 512
#define BATCH   64
#define NN      32
#define HID     1024
#define INW     65
#define OUTW    64
#define ROWS    (T_STEPS * BATCH)   // 32768
#define KVQ     96
#define CHUNK   128                 // scan staging chunk (T_STEPS/CHUNK = 4)

__device__ __forceinline__ float sigmoidf_(float x) { return 1.0f / (1.0f + expf(-x)); }

// ---------------------------------------------------------------- prep
// grid 67: m<65 -> row m of W_in; m==65 -> b_in (+b1); m==66 -> relu(b_mid)
// through layer-2 weights (+b2, sigmoid on q). block 512: tid = hq*128 + ns,
// ns<96 active output col, hq = K-quarter.
__global__ __launch_bounds__(512) void prep_kernel(
    const float* __restrict__ W_in, const float* __restrict__ b_in,
    const float* __restrict__ Wk1, const float* __restrict__ bk1,
    const float* __restrict__ Wv1, const float* __restrict__ bv1,
    const float* __restrict__ Wq1, const float* __restrict__ bq1,
    const float* __restrict__ b_mid,
    const float* __restrict__ Wk2, const float* __restrict__ bk2,
    const float* __restrict__ Wv2, const float* __restrict__ bv2,
    const float* __restrict__ Wq2, const float* __restrict__ bq2,
    float* __restrict__ W1eff, float* __restrict__ b1eff,
    float* __restrict__ const2)
{
    const int m = blockIdx.x;                 // 0..66
    const int tid = threadIdx.x;
    __shared__ float srcv[HID];
    __shared__ float part[512];
    // stage source vector
    for (int h = tid; h < HID; h += 512) {
        float s;
        if (m < INW)       s = W_in[m * HID + h];
        else if (m == INW) s = b_in[h];
        else               s = fmaxf(b_mid[h], 0.f);
        srcv[h] = s;
    }
    __syncthreads();
    const int hq = tid >> 7, ns = tid & 127;  // ns<96 active
    const int sel = ns >> 5, nn = ns & 31;
    const bool layer2 = (m == INW + 1);
    const float* W = layer2 ? (sel == 0 ? Wk2 : sel == 1 ? Wv2 : Wq2)
                            : (sel == 0 ? Wk1 : sel == 1 ? Wv1 : Wq1);
    float acc = 0.f;
    if (ns < KVQ) {
        const int h0 = hq * 256;
        #pragma unroll 8
        for (int hh = 0; hh < 256; ++hh)
            acc = fmaf(srcv[h0 + hh], W[(h0 + hh) * NN + nn], acc);
    }
    part[tid] = acc;
    __syncthreads();
    if (hq == 0 && ns < KVQ) {
        float tot = part[ns] + part[128 + ns] + part[256 + ns] + part[384 + ns];
        if (m < INW) {
            W1eff[m * KVQ + ns] = tot;
        } else if (m == INW) {
            tot += (sel == 0 ? bk1 : sel == 1 ? bv1 : bq1)[nn];
            b1eff[ns] = tot;
        } else {
            tot += (sel == 0 ? bk2 : sel == 1 ? bv2 : bq2)[nn];
            const2[ns] = (sel == 2) ? sigmoidf_(tot) : tot;
        }
    }
}

// ---------------------------------------------------------------- kvq1
// grid 2048, block 256; 16 rows per block; W1eff staged in LDS.
// Output b-major: kvq1[(b*T + t)*96 + col].
__global__ __launch_bounds__(256) void kvq1_kernel(
    const float* __restrict__ x, const float* __restrict__ W1eff,
    const float* __restrict__ b1eff, float* __restrict__ kvq1)
{
    const int tid = threadIdx.x;
    const int r0 = blockIdx.x * 16;
    __shared__ float Ws[INW * KVQ];    // 24.4 KB
    __shared__ float xs[16 * INW];     // 4.1 KB
    __shared__ float bs[KVQ];
    for (int i = tid; i < INW * KVQ; i += 256) Ws[i] = W1eff[i];
    for (int i = tid; i < 16 * INW; i += 256) xs[i] = x[r0 * INW + i];
    if (tid < KVQ) bs[tid] = b1eff[tid];
    __syncthreads();
    const int rr = tid >> 4;           // 0..15
    const int c0 = (tid & 15) * 6;     // cols [c0, c0+6)
    float acc[6];
    #pragma unroll
    for (int k = 0; k < 6; ++k) acc[k] = bs[c0 + k];
    #pragma unroll 5
    for (int m = 0; m < INW; ++m) {
        const float xv = xs[rr * INW + m];
        #pragma unroll
        for (int k = 0; k < 6; ++k)
            acc[k] = fmaf(xv, Ws[m * KVQ + c0 + k], acc[k]);
    }
    const int g = r0 + rr;             // = t*64 + b
    const int t = g >> 6, b = g & 63;
    float* o = kvq1 + (b * T_STEPS + t) * KVQ;
    #pragma unroll
    for (int k = 0; k < 6; ++k) {
        const int col = c0 + k;
        o[col] = (col >= 2 * NN) ? sigmoidf_(acc[k]) : acc[k];
    }
}

// ---------------------------------------------------------------- scan
// grid 256 = b*4+iq, block 256. i = iq*8 + (tid>>5), j = tid&31.
// kvq b-major [b][t][96]. Stages CHUNK steps x 40 floats (k:8, v:32) into
// double-buffered LDS. Spike bits accumulate in registers (one uint32 per
// 32-step window), LDS bit-transpose per chunk -> coalesced mask stores.
// No convergent ops in the hot loop -> compiler batches ds_reads.
__global__ __launch_bounds__(256) void scan_kernel(
    const float* __restrict__ kvq, unsigned int* __restrict__ masks)
{
    const int blk = blockIdx.x;
    const int b = blk >> 2, iq = blk & 3;
    const int tid = threadIdx.x;
    const int ksub = tid >> 5;         // 0..7 (i_local)
    const int j = tid & 31;
    __shared__ float buf[2][CHUNK * 40];        // 40 KB
    __shared__ unsigned int bits[4][8 * 33];    // 4 windows x (ii x j, pad 33)
    const float* base = kvq + b * T_STEPS * KVQ;

    // per-thread staging slots: l = tid + 256*r, r<5 -> (dt, seg)
    int goff[5], loff[5];
    #pragma unroll
    for (int r = 0; r < 5; ++r) {
        const int l = tid + 256 * r;
        const int dt = l / 10, s = l - 10 * dt;
        goff[r] = dt * KVQ + ((s < 2) ? (iq * 8 + 4 * s) : (2 * NN + 4 * (s - 2)));
        loff[r] = dt * 40 + ((s < 2) ? 4 * s : 8 + 4 * (s - 2));
    }
    float4 reg[5];
    #pragma unroll
    for (int r = 0; r < 5; ++r) reg[r] = *(const float4*)(base + goff[r]);
    #pragma unroll
    for (int r = 0; r < 5; ++r) *(float4*)&buf[0][loff[r]] = reg[r];
    __syncthreads();

    float mem = 0.f;
    for (int c = 0; c < T_STEPS / CHUNK; ++c) {
        const int cur = c & 1;
        if (c < T_STEPS / CHUNK - 1) {
            const float* nb = base + (c + 1) * CHUNK * KVQ;
            #pragma unroll
            for (int r = 0; r < 5; ++r) reg[r] = *(const float4*)(nb + goff[r]);
        }
        const float* kbase = &buf[cur][ksub];
        const float* vbase = &buf[cur][8 + j];
        unsigned int u = 0;
        #pragma unroll 16
        for (int dt = 0; dt < CHUNK; ++dt) {
            const float k = kbase[dt * 40];
            const float v = vbase[dt * 40];
            mem = fmaf(0.9f, mem, k * v);
            const bool s = mem > 1.0f;
            if (s) mem -= 1.0f;
            u |= (s ? 1u : 0u) << (dt & 31);
            if ((dt & 31) == 31) { bits[dt >> 5][ksub * 33 + j] = u; u = 0; }
        }
        __syncthreads();   // bits complete; buf[cur] fully consumed
        if (c < T_STEPS / CHUNK - 1) {
            #pragma unroll
            for (int r = 0; r < 5; ++r) *(float4*)&buf[cur ^ 1][loff[r]] = reg[r];
        }
        // bit-transpose: thread -> (odt = tid>>3, oii = tid&7)
        {
            const int oii = tid & 7, odt = tid >> 3;
            #pragma unroll
            for (int w4 = 0; w4 < 4; ++w4) {
                unsigned int word = 0;
                #pragma unroll
                for (int jj = 0; jj < 32; ++jj)
                    word |= ((bits[w4][oii * 33 + jj] >> odt) & 1u) << jj;
                masks[(c * CHUNK + w4 * 32 + odt) * (BATCH * NN)
                      + b * NN + iq * 8 + oii] = word;
            }
        }
        __syncthreads();   // buf[cur^1] ready; bits reusable
    }
}

// ---------------------------------------------------------------- mid
// Fast path (ballot over coalesced mask load): copy const2, no barrier.
__global__ __launch_bounds__(128) void mid_kernel(
    const unsigned int* __restrict__ masks1, const float* __restrict__ kvq1,
    const float* __restrict__ W_mid, const float* __restrict__ b_mid,
    const float* __restrict__ Wk2, const float* __restrict__ bk2,
    const float* __restrict__ Wv2, const float* __restrict__ bv2,
    const float* __restrict__ Wq2, const float* __restrict__ bq2,
    const float* __restrict__ const2, float* __restrict__ kvq2)
{
    const int row = blockIdx.x;        // t*64+b
    const int tid = threadIdx.x;       // 128
    const int t = row >> 6, b = row & 63;
    const int brow = (b * T_STEPS + t) * KVQ;
    const unsigned int m0 = masks1[row * NN + (tid & 31)];
    if (__ballot(m0 != 0) == 0ULL) {   // wave-uniform, consistent across block
        if (tid < KVQ) kvq2[brow + tid] = const2[tid];
        return;
    }
    __shared__ unsigned int ms[NN];
    __shared__ float h2[HID];
    if (tid < NN) ms[tid] = m0;
    for (int c = tid; c < HID; c += 128) h2[c] = b_mid[c];
    __syncthreads();
    for (int i = 0; i < NN; ++i) {
        unsigned int m = ms[i];
        if (!m) continue;
        const float qv = kvq1[brow + 2 * NN + i];
        while (m) {
            const int jj = __ffs(m) - 1; m &= m - 1;
            const float* wrow = W_mid + (i * NN + jj) * HID;
            for (int c = tid; c < HID; c += 128) h2[c] = fmaf(qv, wrow[c], h2[c]);
        }
    }
    __syncthreads();
    for (int c = tid; c < HID; c += 128) h2[c] = fmaxf(h2[c], 0.f);
    __syncthreads();
    if (tid < KVQ) {
        const int sel = tid >> 5, nn = tid & 31;
        const float* W2 = sel == 0 ? Wk2 : sel == 1 ? Wv2 : Wq2;
        float acc = (sel == 0 ? bk2 : sel == 1 ? bv2 : bq2)[nn];
        for (int c = 0; c < HID; ++c) acc = fmaf(h2[c], W2[c * NN + nn], acc);
        if (sel == 2) acc = sigmoidf_(acc);
        kvq2[brow + tid] = acc;
    }
}

// ---------------------------------------------------------------- out
__global__ __launch_bounds__(64) void out_kernel(
    const unsigned int* __restrict__ masks2, const float* __restrict__ kvq2,
    const float* __restrict__ W_out, const float* __restrict__ b_out,
    float* __restrict__ y)
{
    const int row = blockIdx.x;        // t*64+b
    const int tid = threadIdx.x;       // 64
    const int t = row >> 6, b = row & 63;
    const unsigned int m0 = masks2[row * NN + (tid & 31)];
    if (__ballot(m0 != 0) == 0ULL) {
        y[row * OUTW + tid] = sigmoidf_(b_out[tid]);
        return;
    }
    __shared__ unsigned int ms[NN];
    if (tid < NN) ms[tid] = m0;
    __syncthreads();
    float acc = b_out[tid];
    for (int i = 0; i < NN; ++i) {
        unsigned int m = ms[i];
        if (!m) continue;
        const float qv = kvq2[(b * T_STEPS + t) * KVQ + 2 * NN + i];
        while (m) {
            const int jj = __ffs(m) - 1; m &= m - 1;
            acc = fmaf(qv, W_out[(i * NN + jj) * OUTW + tid], acc);
        }
    }
    y[row * OUTW + tid] = sigmoidf_(acc);
}

// ---------------------------------------------------------------- launch
extern "C" void kernel_launch(void* const* d_in, const int* in_sizes, int n_in,
                              void* d_out, int out_size, void* d_ws, size_t ws_size,
                              hipStream_t stream)
{
    const float* x     = (const float*)d_in[0];
    const float* W_in  = (const float*)d_in[1];
    const float* b_in  = (const float*)d_in[2];
    const float* Wk1   = (const float*)d_in[3];
    const float* bk1   = (const float*)d_in[4];
    const float* Wv1   = (const float*)d_in[5];
    const float* bv1   = (const float*)d_in[6];
    const float* Wq1   = (const float*)d_in[7];
    const float* bq1   = (const float*)d_in[8];
    const float* W_mid = (const float*)d_in[9];
    const float* b_mid = (const float*)d_in[10];
    const float* Wk2   = (const float*)d_in[11];
    const float* bk2   = (const float*)d_in[12];
    const float* Wv2   = (const float*)d_in[13];
    const float* bv2   = (const float*)d_in[14];
    const float* Wq2   = (const float*)d_in[15];
    const float* bq2   = (const float*)d_in[16];
    const float* W_out = (const float*)d_in[17];
    const float* b_out = (const float*)d_in[18];
    float* y = (float*)d_out;

    float* ws = (float*)d_ws;
    float* W1eff  = ws;                                // 65*96 = 6240
    float* b1eff  = ws + 6240;                         // 96
    float* const2 = ws + 6336;                         // 96
    float* kvq1   = ws + 8192;                         // 32768*96, b-major
    float* kvq2   = ws + 8192 + 3145728;               // b-major
    unsigned int* masks1 = (unsigned int*)(ws + 8192 + 2 * 3145728);
    unsigned int* masks2 = (unsigned int*)(ws + 8192 + 2 * 3145728 + 1048576);

    prep_kernel<<<INW + 2, 512, 0, stream>>>(W_in, b_in, Wk1, bk1, Wv1, bv1, Wq1, bq1,
                                             b_mid, Wk2, bk2, Wv2, bv2, Wq2, bq2,
                                             W1eff, b1eff, const2);
    kvq1_kernel<<<ROWS / 16, 256, 0, stream>>>(x, W1eff, b1eff, kvq1);
    scan_kernel<<<BATCH * 4, 256, 0, stream>>>(kvq1, masks1);
    mid_kernel<<<ROWS, 128, 0, stream>>>(masks1, kvq1, W_mid, b_mid,
                                         Wk2, bk2, Wv2, bv2, Wq2, bq2, const2, kvq2);
    scan_kernel<<<BATCH * 4, 256, 0, stream>>>(kvq2, masks2);
    out_kernel<<<ROWS, 64, 0, stream>>>(masks2, kvq2, W_out, b_out, y);
}

// Round 4
// 194.804 us; speedup vs baseline: 3.2274x; 1.0870x over previous
//
#include <hip/hip_runtime.h>
#include <math.h>

// Gen2AssocModel forward. T=512, B=64, N=32, HID=1024, SEQ_WIDTH=64.
//   prep:  W1eff = W_in @ [Wk1|Wv1|Wq1] (65x96), b1eff, const2 (kvq2 row for
//          spike-free out1 rows).
//   kvq1:  (32768x65)@(65x96), 4row x 12col register tiles, all-float4 LDS.
//   scan:  2 membranes/thread, LDS double-buffered staging; spike bits in
//          registers; per-window ballots -> dmask[win][b][i][j] t-bit words +
//          rowany[b][iq][win] summary (bit per t).
//   mid:   wave-per-window; clean rows -> const2 vector stores; sparse cold.
//   out:   wave-per-window; clean rows -> sigmoid(b_out) vector stores.
// Workspace ~33.6 MB.

#define T_STEPS 512
#define BATCH   64
#define NN      32
#define HID     1024
#define INW     65
#define OUTW    64
#define ROWS    (T_STEPS * BATCH)   // 32768
#define KVQ     96
#define CHUNK   128                 // scan staging chunk (4 chunks, 4 windows each)

__device__ __forceinline__ float sigmoidf_(float x) { return 1.0f / (1.0f + expf(-x)); }

// ---------------------------------------------------------------- prep
// grid 67: m<65 -> row m of W_in; m==65 -> b_in (+b1); m==66 -> relu(b_mid)
// through layer-2 weights (+b2, sigmoid on q). block 512.
__global__ __launch_bounds__(512) void prep_kernel(
    const float* __restrict__ W_in, const float* __restrict__ b_in,
    const float* __restrict__ Wk1, const float* __restrict__ bk1,
    const float* __restrict__ Wv1, const float* __restrict__ bv1,
    const float* __restrict__ Wq1, const float* __restrict__ bq1,
    const float* __restrict__ b_mid,
    const float* __restrict__ Wk2, const float* __restrict__ bk2,
    const float* __restrict__ Wv2, const float* __restrict__ bv2,
    const float* __restrict__ Wq2, const float* __restrict__ bq2,
    float* __restrict__ W1eff, float* __restrict__ b1eff,
    float* __restrict__ const2)
{
    const int m = blockIdx.x;                 // 0..66
    const int tid = threadIdx.x;
    __shared__ float srcv[HID];
    __shared__ float part[512];
    for (int h = tid; h < HID; h += 512) {
        float s;
        if (m < INW)       s = W_in[m * HID + h];
        else if (m == INW) s = b_in[h];
        else               s = fmaxf(b_mid[h], 0.f);
        srcv[h] = s;
    }
    __syncthreads();
    const int hq = tid >> 7, ns = tid & 127;  // ns<96 active
    const int sel = ns >> 5, nn = ns & 31;
    const bool layer2 = (m == INW + 1);
    const float* W = layer2 ? (sel == 0 ? Wk2 : sel == 1 ? Wv2 : Wq2)
                            : (sel == 0 ? Wk1 : sel == 1 ? Wv1 : Wq1);
    float acc = 0.f;
    if (ns < KVQ) {
        const int h0 = hq * 256;
        #pragma unroll 8
        for (int hh = 0; hh < 256; ++hh)
            acc = fmaf(srcv[h0 + hh], W[(h0 + hh) * NN + nn], acc);
    }
    part[tid] = acc;
    __syncthreads();
    if (hq == 0 && ns < KVQ) {
        float tot = part[ns] + part[128 + ns] + part[256 + ns] + part[384 + ns];
        if (m < INW) {
            W1eff[m * KVQ + ns] = tot;
        } else if (m == INW) {
            tot += (sel == 0 ? bk1 : sel == 1 ? bv1 : bq1)[nn];
            b1eff[ns] = tot;
        } else {
            tot += (sel == 0 ? bk2 : sel == 1 ? bv2 : bq2)[nn];
            const2[ns] = (sel == 2) ? sigmoidf_(tot) : tot;
        }
    }
}

// ---------------------------------------------------------------- kvq1
// grid 256, block 256. 128 rows/block; thread = 4 rows x 12 cols.
// xsT transposed in LDS (pad 132), all reads float4, conflict-free.
__global__ __launch_bounds__(256) void kvq1_kernel(
    const float* __restrict__ x, const float* __restrict__ W1eff,
    const float* __restrict__ b1eff, float* __restrict__ kvq1)
{
    const int tid = threadIdx.x;
    const int r0 = blockIdx.x * 128;
    __shared__ float Ws[INW * KVQ];        // 24.4 KB
    __shared__ float xsT[INW * 132];       // 34.3 KB  [m][row], pad 132
    __shared__ float bs[KVQ];
    for (int i4 = tid; i4 < (INW * KVQ) / 4; i4 += 256)
        ((float4*)Ws)[i4] = ((const float4*)W1eff)[i4];
    for (int l = tid; l < 128 * INW; l += 256) {
        const int r = l / INW, m = l - r * INW;
        xsT[m * 132 + r] = x[(size_t)(r0 + r) * INW + m];
    }
    if (tid < KVQ) bs[tid] = b1eff[tid];
    __syncthreads();
    const int rg = tid >> 3;          // 0..31 -> rows rg*4..+3
    const int c0 = (tid & 7) * 12;    // cols [c0, c0+12)
    float acc[4][12];
    #pragma unroll
    for (int r = 0; r < 4; ++r)
        #pragma unroll
        for (int k = 0; k < 12; ++k) acc[r][k] = bs[c0 + k];
    for (int m = 0; m < INW; ++m) {
        const float4 xv = *(const float4*)&xsT[m * 132 + rg * 4];
        const float4 w0 = *(const float4*)&Ws[m * KVQ + c0];
        const float4 w1 = *(const float4*)&Ws[m * KVQ + c0 + 4];
        const float4 w2 = *(const float4*)&Ws[m * KVQ + c0 + 8];
        const float xr[4] = {xv.x, xv.y, xv.z, xv.w};
        const float wk[12] = {w0.x, w0.y, w0.z, w0.w, w1.x, w1.y, w1.z, w1.w,
                              w2.x, w2.y, w2.z, w2.w};
        #pragma unroll
        for (int r = 0; r < 4; ++r)
            #pragma unroll
            for (int k = 0; k < 12; ++k)
                acc[r][k] = fmaf(xr[r], wk[k], acc[r][k]);
    }
    #pragma unroll
    for (int r = 0; r < 4; ++r) {
        const int g = r0 + rg * 4 + r;   // = t*64 + b
        const int t = g >> 6, b = g & 63;
        float* o = kvq1 + ((size_t)b * T_STEPS + t) * KVQ + c0;
        float v[12];
        #pragma unroll
        for (int k = 0; k < 12; ++k)
            v[k] = (c0 + k >= 2 * NN) ? sigmoidf_(acc[r][k]) : acc[r][k];
        *(float4*)&o[0] = make_float4(v[0], v[1], v[2], v[3]);
        *(float4*)&o[4] = make_float4(v[4], v[5], v[6], v[7]);
        *(float4*)&o[8] = make_float4(v[8], v[9], v[10], v[11]);
    }
}

// ---------------------------------------------------------------- scan
// grid 256 = b*4+iq, block 128 (2 waves). thread: j = tid&31, ipair = tid>>5,
// membranes (i0, i0+1) with i0 = iq*8 + ipair*2. kvq b-major [b][t][96].
// Per 32-step window: spike bits in regs, then 32 ballots -> dmask words
// (bit dt over t-window) + shuffle-OR rowany summary.
__global__ __launch_bounds__(128) void scan_kernel(
    const float* __restrict__ kvq, unsigned int* __restrict__ dmask,
    unsigned int* __restrict__ rowany)
{
    const int blk = blockIdx.x;
    const int b = blk >> 2, iq = blk & 3;
    const int tid = threadIdx.x;
    const int j = tid & 31;
    const int ipair = tid >> 5;        // 0..3
    const int i0 = iq * 8 + ipair * 2;
    const int lane = tid & 63;
    const int waveid = tid >> 6;
    __shared__ float buf[2][CHUNK * 40];        // 40 KB
    __shared__ unsigned int wor[4][2];
    const float* base = kvq + (size_t)b * T_STEPS * KVQ;

    // staging: 1280 float4 slots; slot s -> dt = s/10, q = s%10
    // q<2: k cols iq*8+q*4 ; q>=2: v cols 32+(q-2)*4   (v = cols 32..63!)
    int goff[10], loff[10];
    #pragma unroll
    for (int r = 0; r < 10; ++r) {
        const int s = tid + 128 * r;
        const int dt = s / 10, q = s - dt * 10;
        goff[r] = dt * KVQ + ((q < 2) ? (iq * 8 + q * 4) : (NN + (q - 2) * 4));
        loff[r] = dt * 40 + ((q < 2) ? q * 4 : 8 + (q - 2) * 4);
    }
    float4 reg[10];
    #pragma unroll
    for (int r = 0; r < 10; ++r) reg[r] = *(const float4*)(base + goff[r]);
    #pragma unroll
    for (int r = 0; r < 10; ++r) *(float4*)&buf[0][loff[r]] = reg[r];
    __syncthreads();

    float mem0 = 0.f, mem1 = 0.f;
    for (int c = 0; c < T_STEPS / CHUNK; ++c) {
        const int cur = c & 1;
        if (c < T_STEPS / CHUNK - 1) {
            const float* nb = base + (size_t)(c + 1) * CHUNK * KVQ;
            #pragma unroll
            for (int r = 0; r < 10; ++r) reg[r] = *(const float4*)(nb + goff[r]);
        }
        for (int w = 0; w < 4; ++w) {
            unsigned int u0 = 0, u1 = 0;
            #pragma unroll
            for (int d = 0; d < 32; ++d) {
                const int dt = w * 32 + d;
                const float2 kk = *(const float2*)&buf[cur][dt * 40 + ipair * 2];
                const float vv = buf[cur][dt * 40 + 8 + j];
                mem0 = fmaf(0.9f, mem0, kk.x * vv);
                mem1 = fmaf(0.9f, mem1, kk.y * vv);
                const bool s0 = mem0 > 1.f; if (s0) mem0 -= 1.f;
                const bool s1 = mem1 > 1.f; if (s1) mem1 -= 1.f;
                u0 |= (s0 ? 1u : 0u) << d;
                u1 |= (s1 ? 1u : 0u) << d;
            }
            const int wg = c * 4 + w;           // global window 0..15
            unsigned int* dm = dmask + (size_t)(wg * 64 + b) * 1024;
            dm[i0 * 32 + j] = u0;               // coalesced across tid
            dm[(i0 + 1) * 32 + j] = u1;
            unsigned int a = u0 | u1;
            #pragma unroll
            for (int off = 32; off; off >>= 1) a |= __shfl_xor(a, off);
            if (lane == 0) wor[w][waveid] = a;
        }
        __syncthreads();   // buf[cur] consumed, wor complete
        if (c < T_STEPS / CHUNK - 1) {
            #pragma unroll
            for (int r = 0; r < 10; ++r) *(float4*)&buf[cur ^ 1][loff[r]] = reg[r];
        }
        if (tid < 4)
            rowany[(b * 4 + iq) * 16 + c * 4 + tid] = wor[tid][0] | wor[tid][1];
        __syncthreads();
    }
}

// ---------------------------------------------------------------- mid
// grid 256 = b*4+tq, block 256 (4 waves). wave -> window wg = tq*4+wave (32 t).
// Clean rows: const2 via float4 stores (2 rows/instr). Sparse rows cold.
__global__ __launch_bounds__(256) void mid_kernel(
    const unsigned int* __restrict__ rowany1, const unsigned int* __restrict__ dmask1,
    const float* __restrict__ kvq1,
    const float* __restrict__ W_mid, const float* __restrict__ b_mid,
    const float* __restrict__ Wk2, const float* __restrict__ bk2,
    const float* __restrict__ Wv2, const float* __restrict__ bv2,
    const float* __restrict__ Wq2, const float* __restrict__ bq2,
    const float* __restrict__ const2, float* __restrict__ kvq2)
{
    const int blk = blockIdx.x;
    const int b = blk >> 2, tq = blk & 3;
    const int tid = threadIdx.x;
    const int wave = tid >> 6, lane = tid & 63;
    const int wg = tq * 4 + wave;
    __shared__ float h2s[4][HID];
    __shared__ unsigned int mskws[4][NN];
    const int c4 = lane & 31;
    float4 c2v = make_float4(0.f, 0.f, 0.f, 0.f);
    if (c4 < 24) c2v = ((const float4*)const2)[c4];
    const unsigned int or4 = rowany1[(b * 4 + 0) * 16 + wg]
                           | rowany1[(b * 4 + 1) * 16 + wg]
                           | rowany1[(b * 4 + 2) * 16 + wg]
                           | rowany1[(b * 4 + 3) * 16 + wg];
    float* obase = kvq2 + ((size_t)b * T_STEPS + wg * 32) * KVQ;
    if (or4 == 0) {
        #pragma unroll
        for (int d = 0; d < 32; d += 2) {
            const int row = d + (lane >> 5);
            if (c4 < 24) ((float4*)(obase + row * KVQ))[c4] = c2v;
        }
        return;
    }
    for (int d = 0; d < 32; ++d) {
        if (!((or4 >> d) & 1u)) {
            if (lane < 24) ((float4*)(obase + d * KVQ))[lane] = c2v;
            continue;
        }
        // ---- sparse row (cold) ----
        const int t = wg * 32 + d;
        const unsigned int* dmw = dmask1 + (size_t)(wg * 64 + b) * 1024;
        for (int i2 = 0; i2 < NN; i2 += 2) {
            const int i = i2 + (lane >> 5), jj = lane & 31;
            const unsigned int wbits = dmw[i * 32 + jj];
            const unsigned long long bal = __ballot(((wbits >> d) & 1u) != 0);
            if (lane == 0)  mskws[wave][i2] = (unsigned int)bal;
            if (lane == 32) mskws[wave][i2 + 1] = (unsigned int)(bal >> 32);
        }
        for (int cc = lane; cc < HID; cc += 64) h2s[wave][cc] = b_mid[cc];
        const float* qrow = kvq1 + ((size_t)b * T_STEPS + t) * KVQ + 2 * NN;
        for (int i = 0; i < NN; ++i) {
            unsigned int m = mskws[wave][i];
            if (!m) continue;
            const float qv = qrow[i];
            while (m) {
                const int jj = __ffs(m) - 1; m &= m - 1;
                const float* wrow = W_mid + (size_t)(i * NN + jj) * HID;
                for (int cc = lane; cc < HID; cc += 64)
                    h2s[wave][cc] = fmaf(qv, wrow[cc], h2s[wave][cc]);
            }
        }
        for (int cc = lane; cc < HID; cc += 64)
            h2s[wave][cc] = fmaxf(h2s[wave][cc], 0.f);
        for (int pass = 0; pass < 2; ++pass) {
            const int col = (pass == 0) ? lane : 64 + lane;
            if (col < KVQ) {
                const int sel = col >> 5, nn = col & 31;
                const float* W2 = sel == 0 ? Wk2 : sel == 1 ? Wv2 : Wq2;
                float a = (sel == 0 ? bk2 : sel == 1 ? bv2 : bq2)[nn];
                for (int cc = 0; cc < HID; ++cc)
                    a = fmaf(h2s[wave][cc], W2[cc * NN + nn], a);
                obase[d * KVQ + col] = (sel == 2) ? sigmoidf_(a) : a;
            }
        }
    }
}

// ---------------------------------------------------------------- out
// grid 256 = b*4+tq, block 256. Clean rows: sigmoid(b_out) via float4 stores
// (4 rows/instr). Sparse rows cold.
__global__ __launch_bounds__(256) void out_kernel(
    const unsigned int* __restrict__ rowany2, const unsigned int* __restrict__ dmask2,
    const float* __restrict__ kvq2,
    const float* __restrict__ W_out, const float* __restrict__ b_out,
    float* __restrict__ y)
{
    const int blk = blockIdx.x;
    const int b = blk >> 2, tq = blk & 3;
    const int tid = threadIdx.x;
    const int wave = tid >> 6, lane = tid & 63;
    const int wg = tq * 4 + wave;
    __shared__ unsigned int mskws[4][NN];
    const int g16 = lane & 15;
    const float4 bo = ((const float4*)b_out)[g16];
    const float4 sy = make_float4(sigmoidf_(bo.x), sigmoidf_(bo.y),
                                  sigmoidf_(bo.z), sigmoidf_(bo.w));
    const unsigned int or4 = rowany2[(b * 4 + 0) * 16 + wg]
                           | rowany2[(b * 4 + 1) * 16 + wg]
                           | rowany2[(b * 4 + 2) * 16 + wg]
                           | rowany2[(b * 4 + 3) * 16 + wg];
    if (or4 == 0) {
        #pragma unroll
        for (int d = 0; d < 32; d += 4) {
            const int t = wg * 32 + d + (lane >> 4);
            ((float4*)(y + ((size_t)t * 64 + b) * OUTW))[g16] = sy;
        }
        return;
    }
    for (int d = 0; d < 32; ++d) {
        const int t = wg * 32 + d;
        float* yr = y + ((size_t)t * 64 + b) * OUTW;
        if (!((or4 >> d) & 1u)) {
            if (lane < 16) ((float4*)yr)[lane] = sy;
            continue;
        }
        // ---- sparse row (cold) ----
        const unsigned int* dmw = dmask2 + (size_t)(wg * 64 + b) * 1024;
        for (int i2 = 0; i2 < NN; i2 += 2) {
            const int i = i2 + (lane >> 5), jj = lane & 31;
            const unsigned int wbits = dmw[i * 32 + jj];
            const unsigned long long bal = __ballot(((wbits >> d) & 1u) != 0);
            if (lane == 0)  mskws[wave][i2] = (unsigned int)bal;
            if (lane == 32) mskws[wave][i2 + 1] = (unsigned int)(bal >> 32);
        }
        const float* qrow = kvq2 + ((size_t)b * T_STEPS + t) * KVQ + 2 * NN;
        float a = b_out[lane];
        for (int i = 0; i < NN; ++i) {
            unsigned int m = mskws[wave][i];
            if (!m) continue;
            const float qv = qrow[i];
            while (m) {
                const int jj = __ffs(m) - 1; m &= m - 1;
                a = fmaf(qv, W_out[(size_t)(i * NN + jj) * OUTW + lane], a);
            }
        }
        yr[lane] = sigmoidf_(a);
    }
}

// ---------------------------------------------------------------- launch
extern "C" void kernel_launch(void* const* d_in, const int* in_sizes, int n_in,
                              void* d_out, int out_size, void* d_ws, size_t ws_size,
                              hipStream_t stream)
{
    const float* x     = (const float*)d_in[0];
    const float* W_in  = (const float*)d_in[1];
    const float* b_in  = (const float*)d_in[2];
    const float* Wk1   = (const float*)d_in[3];
    const float* bk1   = (const float*)d_in[4];
    const float* Wv1   = (const float*)d_in[5];
    const float* bv1   = (const float*)d_in[6];
    const float* Wq1   = (const float*)d_in[7];
    const float* bq1   = (const float*)d_in[8];
    const float* W_mid = (const float*)d_in[9];
    const float* b_mid = (const float*)d_in[10];
    const float* Wk2   = (const float*)d_in[11];
    const float* bk2   = (const float*)d_in[12];
    const float* Wv2   = (const float*)d_in[13];
    const float* bv2   = (const float*)d_in[14];
    const float* Wq2   = (const float*)d_in[15];
    const float* bq2   = (const float*)d_in[16];
    const float* W_out = (const float*)d_in[17];
    const float* b_out = (const float*)d_in[18];
    float* y = (float*)d_out;

    float* ws = (float*)d_ws;
    float* W1eff  = ws;                                // 6240
    float* b1eff  = ws + 6240;                         // 96
    float* const2 = ws + 6336;                         // 96 (pad to 8192)
    float* kvq1   = ws + 8192;                         // 3,145,728 (b-major)
    float* kvq2   = ws + 8192 + 3145728;               // 3,145,728 (b-major)
    unsigned int* dmask1  = (unsigned int*)(ws + 8192 + 2 * 3145728);   // 1,048,576
    unsigned int* dmask2  = dmask1 + 1048576;                            // 1,048,576
    unsigned int* rowany1 = dmask2 + 1048576;                            // 4096
    unsigned int* rowany2 = rowany1 + 4096;                              // 4096

    prep_kernel<<<INW + 2, 512, 0, stream>>>(W_in, b_in, Wk1, bk1, Wv1, bv1, Wq1, bq1,
                                             b_mid, Wk2, bk2, Wv2, bv2, Wq2, bq2,
                                             W1eff, b1eff, const2);
    kvq1_kernel<<<ROWS / 128, 256, 0, stream>>>(x, W1eff, b1eff, kvq1);
    scan_kernel<<<BATCH * 4, 128, 0, stream>>>(kvq1, dmask1, rowany1);
    mid_kernel<<<BATCH * 4, 256, 0, stream>>>(rowany1, dmask1, kvq1, W_mid, b_mid,
                                              Wk2, bk2, Wv2, bv2, Wq2, bq2,
                                              const2, kvq2);
    scan_kernel<<<BATCH * 4, 128, 0, stream>>>(kvq2, dmask2, rowany2);
    out_kernel<<<BATCH * 4, 256, 0, stream>>>(rowany2, dmask2, kvq2, W_out, b_out, y);
}

// Round 5
// 188.225 us; speedup vs baseline: 3.3402x; 1.0350x over previous
//
#include <hip/hip_runtime.h>
#include <math.h>

// Gen2AssocModel forward. T=512, B=64, N=32, HID=1024, SEQ_WIDTH=64.
//   prep:  W1eff = W_in @ [Wk1|Wv1|Wq1] (65x96), b1eff, const2 (kvq2 row for
//          spike-free out1 rows).
//   kvq1:  (32768x65)@(65x96), 4row x 12col register tiles, all-float4 LDS.
//   scan:  2 membranes/thread, LDS double-buffered chunk staging; hot loop is
//          register double-buffered in batches of 8 steps (forces ds_read
//          batching -- R4 was 1 exposed LDS latency PER STEP, VALUBusy 0.17%).
//          Spike bits -> dmask[win][b][i][j] t-bit words + rowany summary.
//   mid:   wave-per-window; clean rows -> const2 vector stores; sparse cold.
//   out:   wave-per-window; clean rows -> sigmoid(b_out) vector stores.
// Workspace ~33.6 MB.

#define T_STEPS 512
#define BATCH   64
#define NN      32
#define HID     1024
#define INW     65
#define OUTW    64
#define ROWS    (T_STEPS * BATCH)   // 32768
#define KVQ     96
#define CHUNK   128                 // scan staging chunk (4 chunks, 4 windows each)

__device__ __forceinline__ float sigmoidf_(float x) { return 1.0f / (1.0f + expf(-x)); }

// ---------------------------------------------------------------- prep
// grid 67: m<65 -> row m of W_in; m==65 -> b_in (+b1); m==66 -> relu(b_mid)
// through layer-2 weights (+b2, sigmoid on q). block 512.
__global__ __launch_bounds__(512) void prep_kernel(
    const float* __restrict__ W_in, const float* __restrict__ b_in,
    const float* __restrict__ Wk1, const float* __restrict__ bk1,
    const float* __restrict__ Wv1, const float* __restrict__ bv1,
    const float* __restrict__ Wq1, const float* __restrict__ bq1,
    const float* __restrict__ b_mid,
    const float* __restrict__ Wk2, const float* __restrict__ bk2,
    const float* __restrict__ Wv2, const float* __restrict__ bv2,
    const float* __restrict__ Wq2, const float* __restrict__ bq2,
    float* __restrict__ W1eff, float* __restrict__ b1eff,
    float* __restrict__ const2)
{
    const int m = blockIdx.x;                 // 0..66
    const int tid = threadIdx.x;
    __shared__ float srcv[HID];
    __shared__ float part[512];
    for (int h = tid; h < HID; h += 512) {
        float s;
        if (m < INW)       s = W_in[m * HID + h];
        else if (m == INW) s = b_in[h];
        else               s = fmaxf(b_mid[h], 0.f);
        srcv[h] = s;
    }
    __syncthreads();
    const int hq = tid >> 7, ns = tid & 127;  // ns<96 active
    const int sel = ns >> 5, nn = ns & 31;
    const bool layer2 = (m == INW + 1);
    const float* W = layer2 ? (sel == 0 ? Wk2 : sel == 1 ? Wv2 : Wq2)
                            : (sel == 0 ? Wk1 : sel == 1 ? Wv1 : Wq1);
    float acc = 0.f;
    if (ns < KVQ) {
        const int h0 = hq * 256;
        #pragma unroll 8
        for (int hh = 0; hh < 256; ++hh)
            acc = fmaf(srcv[h0 + hh], W[(h0 + hh) * NN + nn], acc);
    }
    part[tid] = acc;
    __syncthreads();
    if (hq == 0 && ns < KVQ) {
        float tot = part[ns] + part[128 + ns] + part[256 + ns] + part[384 + ns];
        if (m < INW) {
            W1eff[m * KVQ + ns] = tot;
        } else if (m == INW) {
            tot += (sel == 0 ? bk1 : sel == 1 ? bv1 : bq1)[nn];
            b1eff[ns] = tot;
        } else {
            tot += (sel == 0 ? bk2 : sel == 1 ? bv2 : bq2)[nn];
            const2[ns] = (sel == 2) ? sigmoidf_(tot) : tot;
        }
    }
}

// ---------------------------------------------------------------- kvq1
// grid 256, block 256. 128 rows/block; thread = 4 rows x 12 cols.
// xsT transposed in LDS (pad 132), all reads float4, conflict-free.
__global__ __launch_bounds__(256) void kvq1_kernel(
    const float* __restrict__ x, const float* __restrict__ W1eff,
    const float* __restrict__ b1eff, float* __restrict__ kvq1)
{
    const int tid = threadIdx.x;
    const int r0 = blockIdx.x * 128;
    __shared__ float Ws[INW * KVQ];        // 24.4 KB
    __shared__ float xsT[INW * 132];       // 34.3 KB  [m][row], pad 132
    __shared__ float bs[KVQ];
    for (int i4 = tid; i4 < (INW * KVQ) / 4; i4 += 256)
        ((float4*)Ws)[i4] = ((const float4*)W1eff)[i4];
    for (int l = tid; l < 128 * INW; l += 256) {
        const int r = l / INW, m = l - r * INW;
        xsT[m * 132 + r] = x[(size_t)(r0 + r) * INW + m];
    }
    if (tid < KVQ) bs[tid] = b1eff[tid];
    __syncthreads();
    const int rg = tid >> 3;          // 0..31 -> rows rg*4..+3
    const int c0 = (tid & 7) * 12;    // cols [c0, c0+12)
    float acc[4][12];
    #pragma unroll
    for (int r = 0; r < 4; ++r)
        #pragma unroll
        for (int k = 0; k < 12; ++k) acc[r][k] = bs[c0 + k];
    for (int m = 0; m < INW; ++m) {
        const float4 xv = *(const float4*)&xsT[m * 132 + rg * 4];
        const float4 w0 = *(const float4*)&Ws[m * KVQ + c0];
        const float4 w1 = *(const float4*)&Ws[m * KVQ + c0 + 4];
        const float4 w2 = *(const float4*)&Ws[m * KVQ + c0 + 8];
        const float xr[4] = {xv.x, xv.y, xv.z, xv.w};
        const float wk[12] = {w0.x, w0.y, w0.z, w0.w, w1.x, w1.y, w1.z, w1.w,
                              w2.x, w2.y, w2.z, w2.w};
        #pragma unroll
        for (int r = 0; r < 4; ++r)
            #pragma unroll
            for (int k = 0; k < 12; ++k)
                acc[r][k] = fmaf(xr[r], wk[k], acc[r][k]);
    }
    #pragma unroll
    for (int r = 0; r < 4; ++r) {
        const int g = r0 + rg * 4 + r;   // = t*64 + b
        const int t = g >> 6, b = g & 63;
        float* o = kvq1 + ((size_t)b * T_STEPS + t) * KVQ + c0;
        float v[12];
        #pragma unroll
        for (int k = 0; k < 12; ++k)
            v[k] = (c0 + k >= 2 * NN) ? sigmoidf_(acc[r][k]) : acc[r][k];
        *(float4*)&o[0] = make_float4(v[0], v[1], v[2], v[3]);
        *(float4*)&o[4] = make_float4(v[4], v[5], v[6], v[7]);
        *(float4*)&o[8] = make_float4(v[8], v[9], v[10], v[11]);
    }
}

// ---------------------------------------------------------------- scan
// grid 256 = b*4+iq, block 128 (2 waves). thread: j = tid&31, ipair = tid>>5,
// membranes (i0, i0+1) with i0 = iq*8 + ipair*2. kvq b-major [b][t][96].
// Hot loop: register double-buffer, 8 steps/batch; 16 independent ds_reads
// for batch bt+1 issue while batch bt's dependent chain computes.
__global__ __launch_bounds__(128) void scan_kernel(
    const float* __restrict__ kvq, unsigned int* __restrict__ dmask,
    unsigned int* __restrict__ rowany)
{
    const int blk = blockIdx.x;
    const int b = blk >> 2, iq = blk & 3;
    const int tid = threadIdx.x;
    const int j = tid & 31;
    const int ipair = tid >> 5;        // 0..3
    const int i0 = iq * 8 + ipair * 2;
    const int lane = tid & 63;
    const int waveid = tid >> 6;
    __shared__ float buf[2][CHUNK * 40];        // 40 KB
    __shared__ unsigned int wor[4][2];
    const float* base = kvq + (size_t)b * T_STEPS * KVQ;

    // staging: 1280 float4 slots; slot s -> dt = s/10, q = s%10
    // q<2: k cols iq*8+q*4 ; q>=2: v cols 32+(q-2)*4. loff == 4*s (contig).
    int goff[10], loff[10];
    #pragma unroll
    for (int r = 0; r < 10; ++r) {
        const int s = tid + 128 * r;
        const int dt = s / 10, q = s - dt * 10;
        goff[r] = dt * KVQ + ((q < 2) ? (iq * 8 + q * 4) : (NN + (q - 2) * 4));
        loff[r] = 4 * s;
    }
    float4 reg[10];
    #pragma unroll
    for (int r = 0; r < 10; ++r) reg[r] = *(const float4*)(base + goff[r]);
    #pragma unroll
    for (int r = 0; r < 10; ++r) *(float4*)&buf[0][loff[r]] = reg[r];
    __syncthreads();

    float mem0 = 0.f, mem1 = 0.f;
    for (int c = 0; c < T_STEPS / CHUNK; ++c) {
        const int cur = c & 1;
        if (c < T_STEPS / CHUNK - 1) {
            const float* nb = base + (size_t)(c + 1) * CHUNK * KVQ;
            #pragma unroll
            for (int r = 0; r < 10; ++r) reg[r] = *(const float4*)(nb + goff[r]);
        }
        const float* Bc = buf[cur];
        // ---- register-pipelined compute: 16 batches x 8 steps ----
        float2 ka[2][8];
        float  va[2][8];
        #pragma unroll
        for (int d = 0; d < 8; ++d) {
            ka[0][d] = *(const float2*)&Bc[d * 40 + ipair * 2];
            va[0][d] = Bc[d * 40 + 8 + j];
        }
        unsigned int u0 = 0, u1 = 0;
        #pragma unroll
        for (int bt = 0; bt < 16; ++bt) {
            const int cb = bt & 1, nb2 = cb ^ 1;
            if (bt < 15) {
                const int o = (bt + 1) * 320;
                #pragma unroll
                for (int d = 0; d < 8; ++d) {
                    ka[nb2][d] = *(const float2*)&Bc[o + d * 40 + ipair * 2];
                    va[nb2][d] = Bc[o + d * 40 + 8 + j];
                }
            }
            #pragma unroll
            for (int d = 0; d < 8; ++d) {
                const float vv = va[cb][d];
                mem0 = fmaf(0.9f, mem0, ka[cb][d].x * vv);
                mem1 = fmaf(0.9f, mem1, ka[cb][d].y * vv);
                const bool s0 = mem0 > 1.f; if (s0) mem0 -= 1.f;
                const bool s1 = mem1 > 1.f; if (s1) mem1 -= 1.f;
                const int sh = ((bt & 3) << 3) + d;
                u0 |= (s0 ? 1u : 0u) << sh;
                u1 |= (s1 ? 1u : 0u) << sh;
            }
            if ((bt & 3) == 3) {
                const int w = bt >> 2;
                const int wg = c * 4 + w;           // global window 0..15
                unsigned int* dm = dmask + (size_t)(wg * 64 + b) * 1024;
                dm[i0 * 32 + j] = u0;
                dm[(i0 + 1) * 32 + j] = u1;
                unsigned int a = u0 | u1;
                #pragma unroll
                for (int off = 32; off; off >>= 1) a |= __shfl_xor(a, off);
                if (lane == 0) wor[w][waveid] = a;
                u0 = 0; u1 = 0;
            }
        }
        __syncthreads();   // buf[cur] consumed, wor complete
        if (c < T_STEPS / CHUNK - 1) {
            #pragma unroll
            for (int r = 0; r < 10; ++r) *(float4*)&buf[cur ^ 1][loff[r]] = reg[r];
        }
        if (tid < 4)
            rowany[(b * 4 + iq) * 16 + c * 4 + tid] = wor[tid][0] | wor[tid][1];
        __syncthreads();
    }
}

// ---------------------------------------------------------------- mid
// grid 256 = b*4+tq, block 256 (4 waves). wave -> window wg = tq*4+wave (32 t).
// Clean rows: const2 via float4 stores (2 rows/instr). Sparse rows cold.
__global__ __launch_bounds__(256) void mid_kernel(
    const unsigned int* __restrict__ rowany1, const unsigned int* __restrict__ dmask1,
    const float* __restrict__ kvq1,
    const float* __restrict__ W_mid, const float* __restrict__ b_mid,
    const float* __restrict__ Wk2, const float* __restrict__ bk2,
    const float* __restrict__ Wv2, const float* __restrict__ bv2,
    const float* __restrict__ Wq2, const float* __restrict__ bq2,
    const float* __restrict__ const2, float* __restrict__ kvq2)
{
    const int blk = blockIdx.x;
    const int b = blk >> 2, tq = blk & 3;
    const int tid = threadIdx.x;
    const int wave = tid >> 6, lane = tid & 63;
    const int wg = tq * 4 + wave;
    __shared__ float h2s[4][HID];
    __shared__ unsigned int mskws[4][NN];
    const int c4 = lane & 31;
    float4 c2v = make_float4(0.f, 0.f, 0.f, 0.f);
    if (c4 < 24) c2v = ((const float4*)const2)[c4];
    const unsigned int or4 = rowany1[(b * 4 + 0) * 16 + wg]
                           | rowany1[(b * 4 + 1) * 16 + wg]
                           | rowany1[(b * 4 + 2) * 16 + wg]
                           | rowany1[(b * 4 + 3) * 16 + wg];
    float* obase = kvq2 + ((size_t)b * T_STEPS + wg * 32) * KVQ;
    if (or4 == 0) {
        #pragma unroll
        for (int d = 0; d < 32; d += 2) {
            const int row = d + (lane >> 5);
            if (c4 < 24) ((float4*)(obase + row * KVQ))[c4] = c2v;
        }
        return;
    }
    for (int d = 0; d < 32; ++d) {
        if (!((or4 >> d) & 1u)) {
            if (lane < 24) ((float4*)(obase + d * KVQ))[lane] = c2v;
            continue;
        }
        // ---- sparse row (cold) ----
        const int t = wg * 32 + d;
        const unsigned int* dmw = dmask1 + (size_t)(wg * 64 + b) * 1024;
        for (int i2 = 0; i2 < NN; i2 += 2) {
            const int i = i2 + (lane >> 5), jj = lane & 31;
            const unsigned int wbits = dmw[i * 32 + jj];
            const unsigned long long bal = __ballot(((wbits >> d) & 1u) != 0);
            if (lane == 0)  mskws[wave][i2] = (unsigned int)bal;
            if (lane == 32) mskws[wave][i2 + 1] = (unsigned int)(bal >> 32);
        }
        for (int cc = lane; cc < HID; cc += 64) h2s[wave][cc] = b_mid[cc];
        const float* qrow = kvq1 + ((size_t)b * T_STEPS + t) * KVQ + 2 * NN;
        for (int i = 0; i < NN; ++i) {
            unsigned int m = mskws[wave][i];
            if (!m) continue;
            const float qv = qrow[i];
            while (m) {
                const int jj = __ffs(m) - 1; m &= m - 1;
                const float* wrow = W_mid + (size_t)(i * NN + jj) * HID;
                for (int cc = lane; cc < HID; cc += 64)
                    h2s[wave][cc] = fmaf(qv, wrow[cc], h2s[wave][cc]);
            }
        }
        for (int cc = lane; cc < HID; cc += 64)
            h2s[wave][cc] = fmaxf(h2s[wave][cc], 0.f);
        for (int pass = 0; pass < 2; ++pass) {
            const int col = (pass == 0) ? lane : 64 + lane;
            if (col < KVQ) {
                const int sel = col >> 5, nn = col & 31;
                const float* W2 = sel == 0 ? Wk2 : sel == 1 ? Wv2 : Wq2;
                float a = (sel == 0 ? bk2 : sel == 1 ? bv2 : bq2)[nn];
                for (int cc = 0; cc < HID; ++cc)
                    a = fmaf(h2s[wave][cc], W2[cc * NN + nn], a);
                obase[d * KVQ + col] = (sel == 2) ? sigmoidf_(a) : a;
            }
        }
    }
}

// ---------------------------------------------------------------- out
// grid 256 = b*4+tq, block 256. Clean rows: sigmoid(b_out) via float4 stores
// (4 rows/instr). Sparse rows cold.
__global__ __launch_bounds__(256) void out_kernel(
    const unsigned int* __restrict__ rowany2, const unsigned int* __restrict__ dmask2,
    const float* __restrict__ kvq2,
    const float* __restrict__ W_out, const float* __restrict__ b_out,
    float* __restrict__ y)
{
    const int blk = blockIdx.x;
    const int b = blk >> 2, tq = blk & 3;
    const int tid = threadIdx.x;
    const int wave = tid >> 6, lane = tid & 63;
    const int wg = tq * 4 + wave;
    __shared__ unsigned int mskws[4][NN];
    const int g16 = lane & 15;
    const float4 bo = ((const float4*)b_out)[g16];
    const float4 sy = make_float4(sigmoidf_(bo.x), sigmoidf_(bo.y),
                                  sigmoidf_(bo.z), sigmoidf_(bo.w));
    const unsigned int or4 = rowany2[(b * 4 + 0) * 16 + wg]
                           | rowany2[(b * 4 + 1) * 16 + wg]
                           | rowany2[(b * 4 + 2) * 16 + wg]
                           | rowany2[(b * 4 + 3) * 16 + wg];
    if (or4 == 0) {
        #pragma unroll
        for (int d = 0; d < 32; d += 4) {
            const int t = wg * 32 + d + (lane >> 4);
            ((float4*)(y + ((size_t)t * 64 + b) * OUTW))[g16] = sy;
        }
        return;
    }
    for (int d = 0; d < 32; ++d) {
        const int t = wg * 32 + d;
        float* yr = y + ((size_t)t * 64 + b) * OUTW;
        if (!((or4 >> d) & 1u)) {
            if (lane < 16) ((float4*)yr)[lane] = sy;
            continue;
        }
        // ---- sparse row (cold) ----
        const unsigned int* dmw = dmask2 + (size_t)(wg * 64 + b) * 1024;
        for (int i2 = 0; i2 < NN; i2 += 2) {
            const int i = i2 + (lane >> 5), jj = lane & 31;
            const unsigned int wbits = dmw[i * 32 + jj];
            const unsigned long long bal = __ballot(((wbits >> d) & 1u) != 0);
            if (lane == 0)  mskws[wave][i2] = (unsigned int)bal;
            if (lane == 32) mskws[wave][i2 + 1] = (unsigned int)(bal >> 32);
        }
        const float* qrow = kvq2 + ((size_t)b * T_STEPS + t) * KVQ + 2 * NN;
        float a = b_out[lane];
        for (int i = 0; i < NN; ++i) {
            unsigned int m = mskws[wave][i];
            if (!m) continue;
            const float qv = qrow[i];
            while (m) {
                const int jj = __ffs(m) - 1; m &= m - 1;
                a = fmaf(qv, W_out[(size_t)(i * NN + jj) * OUTW + lane], a);
            }
        }
        yr[lane] = sigmoidf_(a);
    }
}

// ---------------------------------------------------------------- launch
extern "C" void kernel_launch(void* const* d_in, const int* in_sizes, int n_in,
                              void* d_out, int out_size, void* d_ws, size_t ws_size,
                              hipStream_t stream)
{
    const float* x     = (const float*)d_in[0];
    const float* W_in  = (const float*)d_in[1];
    const float* b_in  = (const float*)d_in[2];
    const float* Wk1   = (const float*)d_in[3];
    const float* bk1   = (const float*)d_in[4];
    const float* Wv1   = (const float*)d_in[5];
    const float* bv1   = (const float*)d_in[6];
    const float* Wq1   = (const float*)d_in[7];
    const float* bq1   = (const float*)d_in[8];
    const float* W_mid = (const float*)d_in[9];
    const float* b_mid = (const float*)d_in[10];
    const float* Wk2   = (const float*)d_in[11];
    const float* bk2   = (const float*)d_in[12];
    const float* Wv2   = (const float*)d_in[13];
    const float* bv2   = (const float*)d_in[14];
    const float* Wq2   = (const float*)d_in[15];
    const float* bq2   = (const float*)d_in[16];
    const float* W_out = (const float*)d_in[17];
    const float* b_out = (const float*)d_in[18];
    float* y = (float*)d_out;

    float* ws = (float*)d_ws;
    float* W1eff  = ws;                                // 6240
    float* b1eff  = ws + 6240;                         // 96
    float* const2 = ws + 6336;                         // 96 (pad to 8192)
    float* kvq1   = ws + 8192;                         // 3,145,728 (b-major)
    float* kvq2   = ws + 8192 + 3145728;               // 3,145,728 (b-major)
    unsigned int* dmask1  = (unsigned int*)(ws + 8192 + 2 * 3145728);   // 1,048,576
    unsigned int* dmask2  = dmask1 + 1048576;                            // 1,048,576
    unsigned int* rowany1 = dmask2 + 1048576;                            // 4096
    unsigned int* rowany2 = rowany1 + 4096;                              // 4096

    prep_kernel<<<INW + 2, 512, 0, stream>>>(W_in, b_in, Wk1, bk1, Wv1, bv1, Wq1, bq1,
                                             b_mid, Wk2, bk2, Wv2, bv2, Wq2, bq2,
                                             W1eff, b1eff, const2);
    kvq1_kernel<<<ROWS / 128, 256, 0, stream>>>(x, W1eff, b1eff, kvq1);
    scan_kernel<<<BATCH * 4, 128, 0, stream>>>(kvq1, dmask1, rowany1);
    mid_kernel<<<BATCH * 4, 256, 0, stream>>>(rowany1, dmask1, kvq1, W_mid, b_mid,
                                              Wk2, bk2, Wv2, bv2, Wq2, bq2,
                                              const2, kvq2);
    scan_kernel<<<BATCH * 4, 128, 0, stream>>>(kvq2, dmask2, rowany2);
    out_kernel<<<BATCH * 4, 256, 0, stream>>>(rowany2, dmask2, kvq2, W_out, b_out, y);
}

// Round 6
// 156.107 us; speedup vs baseline: 4.0274x; 1.2057x over previous
//
#include <hip/hip_runtime.h>
#include <math.h>

// Gen2AssocModel forward. T=512, B=64, N=32, HID=1024, SEQ_WIDTH=64.
//   prep:    W1eff = W_in @ [Wk1|Wv1|Wq1] (65x96), b1eff, const2; zero flags.
//   kvq1:    (32768x65)@(65x96), 4row x 12col register tiles, float4 LDS.
//   scan (3 kernels, speculative segmented):
//     phase1:  8 segments x 64 steps; per membrane-seg linear prefix sum S
//              and running max|p| -> 8x TLP (8 waves/CU vs 1 wave/SIMD).
//     combine: chain S with 0.9^64; certify no-spike via ub=max(M,0)+pmax
//              <= 0.999 (margin >> fp reassoc error, NaN-safe); rowany=0;
//              flag uncertain batches.
//     cleanup: EXACT serial scan (R5 code) for flagged b only.
//   mid/out: rowany fast path -> const rows; sparse cold path exact.
// Workspace ~38 MB.

#define T_STEPS 512
#define BATCH   64
#define NN      32
#define HID     1024
#define INW     65
#define OUTW    64
#define ROWS    (T_STEPS * BATCH)   // 32768
#define KVQ     96
#define CHUNK   128

__device__ __forceinline__ float sigmoidf_(float x) { return 1.0f / (1.0f + expf(-x)); }

// ---------------------------------------------------------------- prep
__global__ __launch_bounds__(512) void prep_kernel(
    const float* __restrict__ W_in, const float* __restrict__ b_in,
    const float* __restrict__ Wk1, const float* __restrict__ bk1,
    const float* __restrict__ Wv1, const float* __restrict__ bv1,
    const float* __restrict__ Wq1, const float* __restrict__ bq1,
    const float* __restrict__ b_mid,
    const float* __restrict__ Wk2, const float* __restrict__ bk2,
    const float* __restrict__ Wv2, const float* __restrict__ bv2,
    const float* __restrict__ Wq2, const float* __restrict__ bq2,
    float* __restrict__ W1eff, float* __restrict__ b1eff,
    float* __restrict__ const2, unsigned int* __restrict__ flags)
{
    const int m = blockIdx.x;                 // 0..66
    const int tid = threadIdx.x;
    if (m == 0 && tid < 128) flags[tid] = 0u; // flags1[64] | flags2[64]
    __shared__ float srcv[HID];
    __shared__ float part[512];
    for (int h = tid; h < HID; h += 512) {
        float s;
        if (m < INW)       s = W_in[m * HID + h];
        else if (m == INW) s = b_in[h];
        else               s = fmaxf(b_mid[h], 0.f);
        srcv[h] = s;
    }
    __syncthreads();
    const int hq = tid >> 7, ns = tid & 127;  // ns<96 active
    const int sel = ns >> 5, nn = ns & 31;
    const bool layer2 = (m == INW + 1);
    const float* W = layer2 ? (sel == 0 ? Wk2 : sel == 1 ? Wv2 : Wq2)
                            : (sel == 0 ? Wk1 : sel == 1 ? Wv1 : Wq1);
    float acc = 0.f;
    if (ns < KVQ) {
        const int h0 = hq * 256;
        #pragma unroll 8
        for (int hh = 0; hh < 256; ++hh)
            acc = fmaf(srcv[h0 + hh], W[(h0 + hh) * NN + nn], acc);
    }
    part[tid] = acc;
    __syncthreads();
    if (hq == 0 && ns < KVQ) {
        float tot = part[ns] + part[128 + ns] + part[256 + ns] + part[384 + ns];
        if (m < INW) {
            W1eff[m * KVQ + ns] = tot;
        } else if (m == INW) {
            tot += (sel == 0 ? bk1 : sel == 1 ? bv1 : bq1)[nn];
            b1eff[ns] = tot;
        } else {
            tot += (sel == 0 ? bk2 : sel == 1 ? bv2 : bq2)[nn];
            const2[ns] = (sel == 2) ? sigmoidf_(tot) : tot;
        }
    }
}

// ---------------------------------------------------------------- kvq1
__global__ __launch_bounds__(256) void kvq1_kernel(
    const float* __restrict__ x, const float* __restrict__ W1eff,
    const float* __restrict__ b1eff, float* __restrict__ kvq1)
{
    const int tid = threadIdx.x;
    const int r0 = blockIdx.x * 128;
    __shared__ float Ws[INW * KVQ];        // 24.4 KB
    __shared__ float xsT[INW * 132];       // 34.3 KB  [m][row], pad 132
    __shared__ float bs[KVQ];
    for (int i4 = tid; i4 < (INW * KVQ) / 4; i4 += 256)
        ((float4*)Ws)[i4] = ((const float4*)W1eff)[i4];
    for (int l = tid; l < 128 * INW; l += 256) {
        const int r = l / INW, m = l - r * INW;
        xsT[m * 132 + r] = x[(size_t)(r0 + r) * INW + m];
    }
    if (tid < KVQ) bs[tid] = b1eff[tid];
    __syncthreads();
    const int rg = tid >> 3;
    const int c0 = (tid & 7) * 12;
    float acc[4][12];
    #pragma unroll
    for (int r = 0; r < 4; ++r)
        #pragma unroll
        for (int k = 0; k < 12; ++k) acc[r][k] = bs[c0 + k];
    for (int m = 0; m < INW; ++m) {
        const float4 xv = *(const float4*)&xsT[m * 132 + rg * 4];
        const float4 w0 = *(const float4*)&Ws[m * KVQ + c0];
        const float4 w1 = *(const float4*)&Ws[m * KVQ + c0 + 4];
        const float4 w2 = *(const float4*)&Ws[m * KVQ + c0 + 8];
        const float xr[4] = {xv.x, xv.y, xv.z, xv.w};
        const float wk[12] = {w0.x, w0.y, w0.z, w0.w, w1.x, w1.y, w1.z, w1.w,
                              w2.x, w2.y, w2.z, w2.w};
        #pragma unroll
        for (int r = 0; r < 4; ++r)
            #pragma unroll
            for (int k = 0; k < 12; ++k)
                acc[r][k] = fmaf(xr[r], wk[k], acc[r][k]);
    }
    #pragma unroll
    for (int r = 0; r < 4; ++r) {
        const int g = r0 + rg * 4 + r;
        const int t = g >> 6, b = g & 63;
        float* o = kvq1 + ((size_t)b * T_STEPS + t) * KVQ + c0;
        float v[12];
        #pragma unroll
        for (int k = 0; k < 12; ++k)
            v[k] = (c0 + k >= 2 * NN) ? sigmoidf_(acc[r][k]) : acc[r][k];
        *(float4*)&o[0] = make_float4(v[0], v[1], v[2], v[3]);
        *(float4*)&o[4] = make_float4(v[4], v[5], v[6], v[7]);
        *(float4*)&o[8] = make_float4(v[8], v[9], v[10], v[11]);
    }
}

// ---------------------------------------------------------------- scan phase 1
// grid 512 = b*8+seg, block 256 (4 waves). thread: 2i x 2j membranes.
// Zero-init linear prefix p over 64 steps; outputs S = p_end, P = max|p|.
__global__ __launch_bounds__(256) void scan_phase1(
    const float* __restrict__ kvq, float* __restrict__ S, float* __restrict__ P)
{
    const int b = blockIdx.x >> 3, seg = blockIdx.x & 7;
    const int tid = threadIdx.x;
    __shared__ float buf[64 * 64];    // 16 KB: [dt][k(32)|v(32)]
    const float* base = kvq + ((size_t)b * T_STEPS + seg * 64) * KVQ;
    #pragma unroll
    for (int r = 0; r < 4; ++r) {
        const int s4 = tid + 256 * r;         // 0..1023
        const int dt = s4 >> 4, q = s4 & 15;
        *(float4*)&buf[dt * 64 + q * 4] = *(const float4*)(base + dt * KVQ + q * 4);
    }
    __syncthreads();
    const int i0 = (tid >> 4) * 2, j0 = (tid & 15) * 2;
    float p00 = 0.f, p01 = 0.f, p10 = 0.f, p11 = 0.f;
    float a00 = 0.f, a01 = 0.f, a10 = 0.f, a11 = 0.f;
    #pragma unroll 16
    for (int dt = 0; dt < 64; ++dt) {
        const float2 kk = *(const float2*)&buf[dt * 64 + i0];
        const float2 vv = *(const float2*)&buf[dt * 64 + 32 + j0];
        p00 = fmaf(0.9f, p00, kk.x * vv.x); a00 = fmaxf(a00, fabsf(p00));
        p01 = fmaf(0.9f, p01, kk.x * vv.y); a01 = fmaxf(a01, fabsf(p01));
        p10 = fmaf(0.9f, p10, kk.y * vv.x); a10 = fmaxf(a10, fabsf(p10));
        p11 = fmaf(0.9f, p11, kk.y * vv.y); a11 = fmaxf(a11, fabsf(p11));
    }
    const size_t o = ((size_t)seg * 64 + b) * 1024;
    *(float2*)&S[o + i0 * 32 + j0]       = make_float2(p00, p01);
    *(float2*)&S[o + (i0 + 1) * 32 + j0] = make_float2(p10, p11);
    *(float2*)&P[o + i0 * 32 + j0]       = make_float2(a00, a01);
    *(float2*)&P[o + (i0 + 1) * 32 + j0] = make_float2(a10, a11);
}

// ---------------------------------------------------------------- scan combine
// grid 256 = b*4+iq, block 256; 1 membrane/thread. Certify no-spike:
// ub = max(M,0)+pmax is a true upper bound on serial mem within the segment
// (0.9^d*M <= max(M,0), p covers the rest); 1e-3 margin covers fp reassoc.
// NaN/Inf-safe: !(x<=y). Clean -> masks are exactly zero; rowany=0.
__global__ __launch_bounds__(256) void scan_combine(
    const float* __restrict__ S, const float* __restrict__ P,
    unsigned int* __restrict__ rowany, unsigned int* __restrict__ flags)
{
    const int b = blockIdx.x >> 2, iq = blockIdx.x & 3;
    const int tid = threadIdx.x;
    const size_t mo = (size_t)b * 1024 + iq * 256 + tid;
    const float c64 = 0.0011790184577738599f;   // 0.9^64
    float M = 0.f;
    bool fl = false;
    #pragma unroll
    for (int g = 0; g < 8; ++g) {
        const float s  = S[(size_t)g * 65536 + mo];
        const float pm = P[(size_t)g * 65536 + mo];
        const float ub = fmaxf(M, 0.f) + pm;
        fl |= !(ub * 1.0001f <= 0.999f);        // flag if near/over threshold
        M = fmaf(c64, M, s);
    }
    if (__ballot(fl) != 0ULL) {
        if ((tid & 63) == 0) atomicOr(&flags[b], 1u);
    }
    if (tid < 16) rowany[(size_t)(b * 4 + iq) * 16 + tid] = 0u;
}

// ---------------------------------------------------------------- scan cleanup
// EXACT serial scan (reference semantics), only for flagged b. grid 256, blk 128.
__global__ __launch_bounds__(128) void scan_cleanup(
    const float* __restrict__ kvq, unsigned int* __restrict__ dmask,
    unsigned int* __restrict__ rowany, const unsigned int* __restrict__ flags)
{
    const int blk = blockIdx.x;
    const int b = blk >> 2, iq = blk & 3;
    if (flags[b] == 0u) return;
    const int tid = threadIdx.x;
    const int j = tid & 31;
    const int ipair = tid >> 5;
    const int i0 = iq * 8 + ipair * 2;
    const int lane = tid & 63;
    const int waveid = tid >> 6;
    __shared__ float buf[2][CHUNK * 40];
    __shared__ unsigned int wor[4][2];
    const float* base = kvq + (size_t)b * T_STEPS * KVQ;
    int goff[10], loff[10];
    #pragma unroll
    for (int r = 0; r < 10; ++r) {
        const int s = tid + 128 * r;
        const int dt = s / 10, q = s - dt * 10;
        goff[r] = dt * KVQ + ((q < 2) ? (iq * 8 + q * 4) : (NN + (q - 2) * 4));
        loff[r] = 4 * s;
    }
    float4 reg[10];
    #pragma unroll
    for (int r = 0; r < 10; ++r) reg[r] = *(const float4*)(base + goff[r]);
    #pragma unroll
    for (int r = 0; r < 10; ++r) *(float4*)&buf[0][loff[r]] = reg[r];
    __syncthreads();
    float mem0 = 0.f, mem1 = 0.f;
    for (int c = 0; c < T_STEPS / CHUNK; ++c) {
        const int cur = c & 1;
        if (c < T_STEPS / CHUNK - 1) {
            const float* nb = base + (size_t)(c + 1) * CHUNK * KVQ;
            #pragma unroll
            for (int r = 0; r < 10; ++r) reg[r] = *(const float4*)(nb + goff[r]);
        }
        const float* Bc = buf[cur];
        float2 ka[2][8];
        float  va[2][8];
        #pragma unroll
        for (int d = 0; d < 8; ++d) {
            ka[0][d] = *(const float2*)&Bc[d * 40 + ipair * 2];
            va[0][d] = Bc[d * 40 + 8 + j];
        }
        unsigned int u0 = 0, u1 = 0;
        #pragma unroll
        for (int bt = 0; bt < 16; ++bt) {
            const int cb = bt & 1, nb2 = cb ^ 1;
            if (bt < 15) {
                const int o = (bt + 1) * 320;
                #pragma unroll
                for (int d = 0; d < 8; ++d) {
                    ka[nb2][d] = *(const float2*)&Bc[o + d * 40 + ipair * 2];
                    va[nb2][d] = Bc[o + d * 40 + 8 + j];
                }
            }
            #pragma unroll
            for (int d = 0; d < 8; ++d) {
                const float vv = va[cb][d];
                mem0 = fmaf(0.9f, mem0, ka[cb][d].x * vv);
                mem1 = fmaf(0.9f, mem1, ka[cb][d].y * vv);
                const bool s0 = mem0 > 1.f; if (s0) mem0 -= 1.f;
                const bool s1 = mem1 > 1.f; if (s1) mem1 -= 1.f;
                const int sh = ((bt & 3) << 3) + d;
                u0 |= (s0 ? 1u : 0u) << sh;
                u1 |= (s1 ? 1u : 0u) << sh;
            }
            if ((bt & 3) == 3) {
                const int w = bt >> 2;
                const int wg = c * 4 + w;
                unsigned int* dm = dmask + (size_t)(wg * 64 + b) * 1024;
                dm[i0 * 32 + j] = u0;
                dm[(i0 + 1) * 32 + j] = u1;
                unsigned int a = u0 | u1;
                #pragma unroll
                for (int off = 32; off; off >>= 1) a |= __shfl_xor(a, off);
                if (lane == 0) wor[w][waveid] = a;
                u0 = 0; u1 = 0;
            }
        }
        __syncthreads();
        if (c < T_STEPS / CHUNK - 1) {
            #pragma unroll
            for (int r = 0; r < 10; ++r) *(float4*)&buf[cur ^ 1][loff[r]] = reg[r];
        }
        if (tid < 4)
            rowany[(b * 4 + iq) * 16 + c * 4 + tid] = wor[tid][0] | wor[tid][1];
        __syncthreads();
    }
}

// ---------------------------------------------------------------- mid
__global__ __launch_bounds__(256) void mid_kernel(
    const unsigned int* __restrict__ rowany1, const unsigned int* __restrict__ dmask1,
    const float* __restrict__ kvq1,
    const float* __restrict__ W_mid, const float* __restrict__ b_mid,
    const float* __restrict__ Wk2, const float* __restrict__ bk2,
    const float* __restrict__ Wv2, const float* __restrict__ bv2,
    const float* __restrict__ Wq2, const float* __restrict__ bq2,
    const float* __restrict__ const2, float* __restrict__ kvq2)
{
    const int blk = blockIdx.x;
    const int b = blk >> 2, tq = blk & 3;
    const int tid = threadIdx.x;
    const int wave = tid >> 6, lane = tid & 63;
    const int wg = tq * 4 + wave;
    __shared__ float h2s[4][HID];
    __shared__ unsigned int mskws[4][NN];
    const int c4 = lane & 31;
    float4 c2v = make_float4(0.f, 0.f, 0.f, 0.f);
    if (c4 < 24) c2v = ((const float4*)const2)[c4];
    const unsigned int or4 = rowany1[(b * 4 + 0) * 16 + wg]
                           | rowany1[(b * 4 + 1) * 16 + wg]
                           | rowany1[(b * 4 + 2) * 16 + wg]
                           | rowany1[(b * 4 + 3) * 16 + wg];
    float* obase = kvq2 + ((size_t)b * T_STEPS + wg * 32) * KVQ;
    if (or4 == 0) {
        #pragma unroll
        for (int d = 0; d < 32; d += 2) {
            const int row = d + (lane >> 5);
            if (c4 < 24) ((float4*)(obase + row * KVQ))[c4] = c2v;
        }
        return;
    }
    for (int d = 0; d < 32; ++d) {
        if (!((or4 >> d) & 1u)) {
            if (lane < 24) ((float4*)(obase + d * KVQ))[lane] = c2v;
            continue;
        }
        const int t = wg * 32 + d;
        const unsigned int* dmw = dmask1 + (size_t)(wg * 64 + b) * 1024;
        for (int i2 = 0; i2 < NN; i2 += 2) {
            const int i = i2 + (lane >> 5), jj = lane & 31;
            const unsigned int wbits = dmw[i * 32 + jj];
            const unsigned long long bal = __ballot(((wbits >> d) & 1u) != 0);
            if (lane == 0)  mskws[wave][i2] = (unsigned int)bal;
            if (lane == 32) mskws[wave][i2 + 1] = (unsigned int)(bal >> 32);
        }
        for (int cc = lane; cc < HID; cc += 64) h2s[wave][cc] = b_mid[cc];
        const float* qrow = kvq1 + ((size_t)b * T_STEPS + t) * KVQ + 2 * NN;
        for (int i = 0; i < NN; ++i) {
            unsigned int m = mskws[wave][i];
            if (!m) continue;
            const float qv = qrow[i];
            while (m) {
                const int jj = __ffs(m) - 1; m &= m - 1;
                const float* wrow = W_mid + (size_t)(i * NN + jj) * HID;
                for (int cc = lane; cc < HID; cc += 64)
                    h2s[wave][cc] = fmaf(qv, wrow[cc], h2s[wave][cc]);
            }
        }
        for (int cc = lane; cc < HID; cc += 64)
            h2s[wave][cc] = fmaxf(h2s[wave][cc], 0.f);
        for (int pass = 0; pass < 2; ++pass) {
            const int col = (pass == 0) ? lane : 64 + lane;
            if (col < KVQ) {
                const int sel = col >> 5, nn = col & 31;
                const float* W2 = sel == 0 ? Wk2 : sel == 1 ? Wv2 : Wq2;
                float a = (sel == 0 ? bk2 : sel == 1 ? bv2 : bq2)[nn];
                for (int cc = 0; cc < HID; ++cc)
                    a = fmaf(h2s[wave][cc], W2[cc * NN + nn], a);
                obase[d * KVQ + col] = (sel == 2) ? sigmoidf_(a) : a;
            }
        }
    }
}

// ---------------------------------------------------------------- out
__global__ __launch_bounds__(256) void out_kernel(
    const unsigned int* __restrict__ rowany2, const unsigned int* __restrict__ dmask2,
    const float* __restrict__ kvq2,
    const float* __restrict__ W_out, const float* __restrict__ b_out,
    float* __restrict__ y)
{
    const int blk = blockIdx.x;
    const int b = blk >> 2, tq = blk & 3;
    const int tid = threadIdx.x;
    const int wave = tid >> 6, lane = tid & 63;
    const int wg = tq * 4 + wave;
    __shared__ unsigned int mskws[4][NN];
    const int g16 = lane & 15;
    const float4 bo = ((const float4*)b_out)[g16];
    const float4 sy = make_float4(sigmoidf_(bo.x), sigmoidf_(bo.y),
                                  sigmoidf_(bo.z), sigmoidf_(bo.w));
    const unsigned int or4 = rowany2[(b * 4 + 0) * 16 + wg]
                           | rowany2[(b * 4 + 1) * 16 + wg]
                           | rowany2[(b * 4 + 2) * 16 + wg]
                           | rowany2[(b * 4 + 3) * 16 + wg];
    if (or4 == 0) {
        #pragma unroll
        for (int d = 0; d < 32; d += 4) {
            const int t = wg * 32 + d + (lane >> 4);
            ((float4*)(y + ((size_t)t * 64 + b) * OUTW))[g16] = sy;
        }
        return;
    }
    for (int d = 0; d < 32; ++d) {
        const int t = wg * 32 + d;
        float* yr = y + ((size_t)t * 64 + b) * OUTW;
        if (!((or4 >> d) & 1u)) {
            if (lane < 16) ((float4*)yr)[lane] = sy;
            continue;
        }
        const unsigned int* dmw = dmask2 + (size_t)(wg * 64 + b) * 1024;
        for (int i2 = 0; i2 < NN; i2 += 2) {
            const int i = i2 + (lane >> 5), jj = lane & 31;
            const unsigned int wbits = dmw[i * 32 + jj];
            const unsigned long long bal = __ballot(((wbits >> d) & 1u) != 0);
            if (lane == 0)  mskws[wave][i2] = (unsigned int)bal;
            if (lane == 32) mskws[wave][i2 + 1] = (unsigned int)(bal >> 32);
        }
        const float* qrow = kvq2 + ((size_t)b * T_STEPS + t) * KVQ + 2 * NN;
        float a = b_out[lane];
        for (int i = 0; i < NN; ++i) {
            unsigned int m = mskws[wave][i];
            if (!m) continue;
            const float qv = qrow[i];
            while (m) {
                const int jj = __ffs(m) - 1; m &= m - 1;
                a = fmaf(qv, W_out[(size_t)(i * NN + jj) * OUTW + lane], a);
            }
        }
        yr[lane] = sigmoidf_(a);
    }
}

// ---------------------------------------------------------------- launch
extern "C" void kernel_launch(void* const* d_in, const int* in_sizes, int n_in,
                              void* d_out, int out_size, void* d_ws, size_t ws_size,
                              hipStream_t stream)
{
    const float* x     = (const float*)d_in[0];
    const float* W_in  = (const float*)d_in[1];
    const float* b_in  = (const float*)d_in[2];
    const float* Wk1   = (const float*)d_in[3];
    const float* bk1   = (const float*)d_in[4];
    const float* Wv1   = (const float*)d_in[5];
    const float* bv1   = (const float*)d_in[6];
    const float* Wq1   = (const float*)d_in[7];
    const float* bq1   = (const float*)d_in[8];
    const float* W_mid = (const float*)d_in[9];
    const float* b_mid = (const float*)d_in[10];
    const float* Wk2   = (const float*)d_in[11];
    const float* bk2   = (const float*)d_in[12];
    const float* Wv2   = (const float*)d_in[13];
    const float* bv2   = (const float*)d_in[14];
    const float* Wq2   = (const float*)d_in[15];
    const float* bq2   = (const float*)d_in[16];
    const float* W_out = (const float*)d_in[17];
    const float* b_out = (const float*)d_in[18];
    float* y = (float*)d_out;

    float* ws = (float*)d_ws;
    float* W1eff  = ws;                                // 6240
    float* b1eff  = ws + 6240;
    float* const2 = ws + 6336;                         // pad to 8192
    float* kvq1   = ws + 8192;                         // 3,145,728
    float* kvq2   = kvq1 + 3145728;                    // 3,145,728
    unsigned int* dmask1  = (unsigned int*)(kvq2 + 3145728);   // 1,048,576
    unsigned int* dmask2  = dmask1 + 1048576;                  // 1,048,576
    unsigned int* rowany1 = dmask2 + 1048576;                  // 4096
    unsigned int* rowany2 = rowany1 + 4096;                    // 4096
    unsigned int* flags   = rowany2 + 4096;                    // 128 (f1|f2)
    float* Sbuf = (float*)(flags + 128);               // 524,288
    float* Pbuf = Sbuf + 524288;                       // 524,288
    unsigned int* flags1 = flags;
    unsigned int* flags2 = flags + 64;

    prep_kernel<<<INW + 2, 512, 0, stream>>>(W_in, b_in, Wk1, bk1, Wv1, bv1, Wq1, bq1,
                                             b_mid, Wk2, bk2, Wv2, bv2, Wq2, bq2,
                                             W1eff, b1eff, const2, flags);
    kvq1_kernel<<<ROWS / 128, 256, 0, stream>>>(x, W1eff, b1eff, kvq1);
    scan_phase1<<<BATCH * 8, 256, 0, stream>>>(kvq1, Sbuf, Pbuf);
    scan_combine<<<BATCH * 4, 256, 0, stream>>>(Sbuf, Pbuf, rowany1, flags1);
    scan_cleanup<<<BATCH * 4, 128, 0, stream>>>(kvq1, dmask1, rowany1, flags1);
    mid_kernel<<<BATCH * 4, 256, 0, stream>>>(rowany1, dmask1, kvq1, W_mid, b_mid,
                                              Wk2, bk2, Wv2, bv2, Wq2, bq2,
                                              const2, kvq2);
    scan_phase1<<<BATCH * 8, 256, 0, stream>>>(kvq2, Sbuf, Pbuf);
    scan_combine<<<BATCH * 4, 256, 0, stream>>>(Sbuf, Pbuf, rowany2, flags2);
    scan_cleanup<<<BATCH * 4, 128, 0, stream>>>(kvq2, dmask2, rowany2, flags2);
    out_kernel<<<BATCH * 4, 256, 0, stream>>>(rowany2, dmask2, kvq2, W_out, b_out, y);
}

// Round 7
// 151.939 us; speedup vs baseline: 4.1379x; 1.0274x over previous
//
#include <hip/hip_runtime.h>
#include <math.h>

// Gen2AssocModel forward. T=512, B=64, N=32, HID=1024, SEQ_WIDTH=64.
// 6 dispatches (launch/fixed cost dominated regime):
//   prep:    W1eff = W_in @ [Wk1|Wv1|Wq1] (65x96), b1eff, const2.
//   kvq1p1:  per (b,seg=64t): GEMM tile -> LDS -> global kvq1, then phase1
//            (zero-init linear prefix S, max|p| P) straight from LDS.
//   cc:      per b: certify no-spike via chained ub bound; clean -> rowany=0;
//            dirty -> EXACT serial replay -> dmask+rowany. (x2, both layers)
//   midp1:   per (b,seg): clean -> const2 rows + CLOSED-FORM S2/P2
//            (S=c2k*c2v*G64, P=|S|); mixed -> exact sparse rows + real phase1.
//   out:     rowany2 fast path -> sigmoid(b_out); sparse cold exact.
// Workspace ~42 MB.

#define T_STEPS 512
#define BATCH   64
#define NN      32
#define HID     1024
#define INW     65
#define OUTW    64
#define KVQ     96

__device__ __forceinline__ float sigmoidf_(float x) { return 1.0f / (1.0f + expf(-x)); }

// ---------------------------------------------------------------- prep
__global__ __launch_bounds__(512) void prep_kernel(
    const float* __restrict__ W_in, const float* __restrict__ b_in,
    const float* __restrict__ Wk1, const float* __restrict__ bk1,
    const float* __restrict__ Wv1, const float* __restrict__ bv1,
    const float* __restrict__ Wq1, const float* __restrict__ bq1,
    const float* __restrict__ b_mid,
    const float* __restrict__ Wk2, const float* __restrict__ bk2,
    const float* __restrict__ Wv2, const float* __restrict__ bv2,
    const float* __restrict__ Wq2, const float* __restrict__ bq2,
    float* __restrict__ W1eff, float* __restrict__ b1eff,
    float* __restrict__ const2)
{
    const int m = blockIdx.x;                 // 0..66
    const int tid = threadIdx.x;
    __shared__ float srcv[HID];
    __shared__ float part[512];
    for (int h = tid; h < HID; h += 512) {
        float s;
        if (m < INW)       s = W_in[m * HID + h];
        else if (m == INW) s = b_in[h];
        else               s = fmaxf(b_mid[h], 0.f);
        srcv[h] = s;
    }
    __syncthreads();
    const int hq = tid >> 7, ns = tid & 127;  // ns<96 active
    const int sel = ns >> 5, nn = ns & 31;
    const bool layer2 = (m == INW + 1);
    const float* W = layer2 ? (sel == 0 ? Wk2 : sel == 1 ? Wv2 : Wq2)
                            : (sel == 0 ? Wk1 : sel == 1 ? Wv1 : Wq1);
    float acc = 0.f;
    if (ns < KVQ) {
        const int h0 = hq * 256;
        #pragma unroll 8
        for (int hh = 0; hh < 256; ++hh)
            acc = fmaf(srcv[h0 + hh], W[(h0 + hh) * NN + nn], acc);
    }
    part[tid] = acc;
    __syncthreads();
    if (hq == 0 && ns < KVQ) {
        float tot = part[ns] + part[128 + ns] + part[256 + ns] + part[384 + ns];
        if (m < INW) {
            W1eff[m * KVQ + ns] = tot;
        } else if (m == INW) {
            tot += (sel == 0 ? bk1 : sel == 1 ? bv1 : bq1)[nn];
            b1eff[ns] = tot;
        } else {
            tot += (sel == 0 ? bk2 : sel == 1 ? bv2 : bq2)[nn];
            const2[ns] = (sel == 2) ? sigmoidf_(tot) : tot;
        }
    }
}

// ---------------------------------------------------------------- kvq1 + phase1 (fused)
// grid 512 = b*8+seg, block 128. Compute 64x96 kvq tile (4rowx12col/thread),
// keep in LDS (stride 100, pad for bank spread), store to global, then run
// phase1 on the LDS tile: per-membrane 64-step zero-init prefix -> S, max|p| -> P.
__global__ __launch_bounds__(128) void kvq1p1_kernel(
    const float* __restrict__ x, const float* __restrict__ W1eff,
    const float* __restrict__ b1eff, float* __restrict__ kvq1,
    float* __restrict__ S, float* __restrict__ P)
{
    const int b = blockIdx.x >> 3, seg = blockIdx.x & 7;
    const int tid = threadIdx.x;
    __shared__ __align__(16) float Ws[INW * KVQ];   // 24.4 KB
    __shared__ __align__(16) float bs[KVQ];
    __shared__ __align__(16) float pool[64 * 100];  // 25.6 KB: xsT then kt
    for (int i4 = tid; i4 < (INW * KVQ) / 4; i4 += 128)
        ((float4*)Ws)[i4] = ((const float4*)W1eff)[i4];
    if (tid < KVQ) bs[tid] = b1eff[tid];
    // xsT[m*68 + r] = x[((seg*64+r)*64 + b)*65 + m]
    for (int l = tid; l < 64 * INW; l += 128) {
        const int r = l / INW, m = l - r * INW;
        pool[m * 68 + r] = x[((size_t)((seg * 64 + r) * 64 + b)) * INW + m];
    }
    __syncthreads();
    const int rg = tid >> 3;          // rows rg*4..+4
    const int c0 = (tid & 7) * 12;    // cols c0..+12
    float acc[4][12];
    #pragma unroll
    for (int r = 0; r < 4; ++r)
        #pragma unroll
        for (int k = 0; k < 12; ++k) acc[r][k] = bs[c0 + k];
    #pragma unroll 5
    for (int m = 0; m < INW; ++m) {
        const float4 xv = *(const float4*)&pool[m * 68 + rg * 4];
        const float4 w0 = *(const float4*)&Ws[m * KVQ + c0];
        const float4 w1 = *(const float4*)&Ws[m * KVQ + c0 + 4];
        const float4 w2 = *(const float4*)&Ws[m * KVQ + c0 + 8];
        const float xr[4] = {xv.x, xv.y, xv.z, xv.w};
        const float wk[12] = {w0.x, w0.y, w0.z, w0.w, w1.x, w1.y, w1.z, w1.w,
                              w2.x, w2.y, w2.z, w2.w};
        #pragma unroll
        for (int r = 0; r < 4; ++r)
            #pragma unroll
            for (int k = 0; k < 12; ++k)
                acc[r][k] = fmaf(xr[r], wk[k], acc[r][k]);
    }
    __syncthreads();   // xsT dead; pool becomes kt[row*100 + col]
    #pragma unroll
    for (int r = 0; r < 4; ++r) {
        const int row = rg * 4 + r;
        float v[12];
        #pragma unroll
        for (int k = 0; k < 12; ++k)
            v[k] = (c0 + k >= 2 * NN) ? sigmoidf_(acc[r][k]) : acc[r][k];
        float* kt = &pool[row * 100 + c0];
        *(float4*)&kt[0] = make_float4(v[0], v[1], v[2], v[3]);
        *(float4*)&kt[4] = make_float4(v[4], v[5], v[6], v[7]);
        *(float4*)&kt[8] = make_float4(v[8], v[9], v[10], v[11]);
        float* o = kvq1 + ((size_t)b * T_STEPS + seg * 64 + row) * KVQ + c0;
        *(float4*)&o[0] = make_float4(v[0], v[1], v[2], v[3]);
        *(float4*)&o[4] = make_float4(v[4], v[5], v[6], v[7]);
        *(float4*)&o[8] = make_float4(v[8], v[9], v[10], v[11]);
    }
    __syncthreads();
    // phase1 from LDS tile: thread -> membranes (i0..i0+8, j)
    const int i0 = (tid >> 5) * 8, j = tid & 31;
    float p[8], am[8];
    #pragma unroll
    for (int r = 0; r < 8; ++r) { p[r] = 0.f; am[r] = 0.f; }
    for (int tt = 0; tt < 16; ++tt) {
        float4 k0[4], k1[4]; float vv[4];
        #pragma unroll
        for (int d2 = 0; d2 < 4; ++d2) {
            const int t = tt * 4 + d2;
            k0[d2] = *(const float4*)&pool[t * 100 + i0];
            k1[d2] = *(const float4*)&pool[t * 100 + i0 + 4];
            vv[d2] = pool[t * 100 + 32 + j];
        }
        #pragma unroll
        for (int d2 = 0; d2 < 4; ++d2) {
            const float kf[8] = {k0[d2].x, k0[d2].y, k0[d2].z, k0[d2].w,
                                 k1[d2].x, k1[d2].y, k1[d2].z, k1[d2].w};
            #pragma unroll
            for (int r = 0; r < 8; ++r) {
                p[r] = fmaf(0.9f, p[r], kf[r] * vv[d2]);
                am[r] = fmaxf(am[r], fabsf(p[r]));
            }
        }
    }
    const size_t o = ((size_t)seg * 64 + b) * 1024;
    #pragma unroll
    for (int r = 0; r < 8; ++r) {
        S[o + (i0 + r) * 32 + j] = p[r];
        P[o + (i0 + r) * 32 + j] = am[r];
    }
}

// ---------------------------------------------------------------- cc (combine+cleanup)
// grid 64 (per b), block 256. Hot: chained cert over 8 segs; clean -> zero
// rowany. Dirty (cold): exact serial replay of the full T from kvq ->
// dmask + rowany. Shared for both layers via pointers.
__global__ __launch_bounds__(256) void cc_kernel(
    const float* __restrict__ S, const float* __restrict__ P,
    const float* __restrict__ kvq,
    unsigned int* __restrict__ rowany, unsigned int* __restrict__ dmask)
{
    const int b = blockIdx.x;
    const int tid = threadIdx.x;
    const float c64 = 0.0011790184577738599f;   // 0.9^64
    float M[4] = {0.f, 0.f, 0.f, 0.f};
    bool fl = false;
    #pragma unroll
    for (int g = 0; g < 8; ++g) {
        #pragma unroll
        for (int k = 0; k < 4; ++k) {
            const size_t o = (size_t)g * 65536 + (size_t)b * 1024 + k * 256 + tid;
            const float s = S[o], pm = P[o];
            const float ub = fmaxf(M[k], 0.f) + pm;
            fl |= !(ub * 1.0001f <= 0.999f);
            M[k] = fmaf(c64, M[k], s);
        }
    }
    __shared__ unsigned int flr[4];
    const unsigned long long bal = __ballot(fl);
    if ((tid & 63) == 0) flr[tid >> 6] = (bal != 0ULL) ? 1u : 0u;
    __syncthreads();
    if ((flr[0] | flr[1] | flr[2] | flr[3]) == 0u) {
        if (tid < 64) rowany[b * 64 + tid] = 0u;
        return;
    }
    // ---- cold: exact serial replay ----
    __shared__ float buf[64 * 64];   // 16 KB: [dt][k(32)|v(32)]
    const int j = tid & 31, ig = tid >> 5;   // membranes i = ig*4..+4
    const int wavei = tid >> 6;              // wave covers iq = wavei
    float mem[4] = {0.f, 0.f, 0.f, 0.f};
    unsigned int u[4] = {0u, 0u, 0u, 0u};
    for (int c = 0; c < 8; ++c) {
        __syncthreads();
        #pragma unroll
        for (int r = 0; r < 4; ++r) {
            const int s4 = tid + 256 * r;          // 1024 float4 slots
            const int dt = s4 >> 4, q = s4 & 15;   // cols 0..63 = k|v
            *(float4*)&buf[dt * 64 + q * 4] =
                *(const float4*)(kvq + ((size_t)b * T_STEPS + c * 64 + dt) * KVQ + q * 4);
        }
        __syncthreads();
        for (int dt = 0; dt < 64; ++dt) {
            const float4 kk = *(const float4*)&buf[dt * 64 + ig * 4];
            const float vv = buf[dt * 64 + 32 + j];
            const float kf[4] = {kk.x, kk.y, kk.z, kk.w};
            #pragma unroll
            for (int r = 0; r < 4; ++r) {
                mem[r] = fmaf(0.9f, mem[r], kf[r] * vv);
                const bool s = mem[r] > 1.f; if (s) mem[r] -= 1.f;
                u[r] |= (s ? 1u : 0u) << (dt & 31);
            }
            if ((dt & 31) == 31) {
                const int wg = c * 2 + (dt >> 5);
                unsigned int* dm = dmask + (size_t)(wg * 64 + b) * 1024;
                unsigned int a = 0;
                #pragma unroll
                for (int r = 0; r < 4; ++r) {
                    dm[(ig * 4 + r) * 32 + j] = u[r];
                    a |= u[r]; u[r] = 0u;
                }
                #pragma unroll
                for (int off = 32; off; off >>= 1) a |= __shfl_xor(a, off);
                if ((tid & 63) == 0) rowany[(b * 4 + wavei) * 16 + wg] = a;
            }
        }
    }
}

// ---------------------------------------------------------------- mid + phase1 (fused)
// grid 512 = b*8+seg, block 128. Fast (no spikes in windows 2seg,2seg+1):
// const2 rows to kvq2 + closed-form S2/P2 (S=c2k*c2v*G64, P=|S|; monotone
// ramp => max at t=63; cert margin absorbs fp diff). Mixed: exact rows into
// LDS kt2, real phase1.
__global__ __launch_bounds__(128) void midp1_kernel(
    const unsigned int* __restrict__ rowany1, const unsigned int* __restrict__ dmask1,
    const float* __restrict__ kvq1,
    const float* __restrict__ W_mid, const float* __restrict__ b_mid,
    const float* __restrict__ Wk2, const float* __restrict__ bk2,
    const float* __restrict__ Wv2, const float* __restrict__ bv2,
    const float* __restrict__ Wq2, const float* __restrict__ bq2,
    const float* __restrict__ const2, float* __restrict__ kvq2,
    float* __restrict__ S2, float* __restrict__ P2)
{
    const int b = blockIdx.x >> 3, seg = blockIdx.x & 7;
    const int tid = threadIdx.x;
    const int w0 = seg * 2;
    const unsigned int orA = rowany1[(b * 4 + 0) * 16 + w0] | rowany1[(b * 4 + 1) * 16 + w0]
                           | rowany1[(b * 4 + 2) * 16 + w0] | rowany1[(b * 4 + 3) * 16 + w0];
    const unsigned int orB = rowany1[(b * 4 + 0) * 16 + w0 + 1] | rowany1[(b * 4 + 1) * 16 + w0 + 1]
                           | rowany1[(b * 4 + 2) * 16 + w0 + 1] | rowany1[(b * 4 + 3) * 16 + w0 + 1];
    __shared__ __align__(16) float c2s[KVQ];
    if (tid < KVQ) c2s[tid] = const2[tid];
    __syncthreads();
    float* obase = kvq2 + ((size_t)b * T_STEPS + seg * 64) * KVQ;
    const size_t o2 = ((size_t)seg * 64 + b) * 1024;
    const int i0 = (tid >> 5) * 8, j = tid & 31;
    const float G64 = 9.988209815422261f;       // (1-0.9^64)/0.1
    if ((orA | orB) == 0u) {
        for (int l = tid; l < 64 * 24; l += 128) {
            const int row = l / 24, c4 = l - row * 24;
            *(float4*)&obase[row * KVQ + c4 * 4] = ((const float4*)c2s)[c4];
        }
        #pragma unroll
        for (int r = 0; r < 8; ++r) {
            const float s = c2s[i0 + r] * c2s[32 + j] * G64;
            S2[o2 + (i0 + r) * 32 + j] = s;
            P2[o2 + (i0 + r) * 32 + j] = fabsf(s);
        }
        return;
    }
    // ---- mixed (cold) ----
    __shared__ __align__(16) float kt2[64 * 64];   // 16 KB (k,v)
    __shared__ float h2[HID];
    __shared__ unsigned int msk[NN];
    for (int d = 0; d < 64; ++d) {
        const unsigned int orw = (d < 32) ? orA : orB;
        const int bit = d & 31;
        if (!((orw >> bit) & 1u)) {
            if (tid < 16) *(float4*)&kt2[d * 64 + tid * 4] = ((const float4*)c2s)[tid];
            if (tid < 24) *(float4*)&obase[d * KVQ + tid * 4] = ((const float4*)c2s)[tid];
        } else {
            const int wg = w0 + (d >> 5);
            const unsigned int* dmw = dmask1 + (size_t)(wg * 64 + b) * 1024;
            for (int i2 = 0; i2 < NN; i2 += 4) {
                const int i = i2 + (tid >> 5);
                const unsigned int wb = dmw[i * 32 + (tid & 31)];
                const unsigned long long balm = __ballot(((wb >> bit) & 1u) != 0);
                const int ibase = i2 + (tid >> 6) * 2;
                if ((tid & 63) == 0)  msk[ibase]     = (unsigned int)balm;
                if ((tid & 63) == 32) msk[ibase + 1] = (unsigned int)(balm >> 32);
            }
            for (int cc = tid; cc < HID; cc += 128) h2[cc] = b_mid[cc];
            __syncthreads();
            const float* qrow = kvq1 + ((size_t)b * T_STEPS + seg * 64 + d) * KVQ + 2 * NN;
            for (int i = 0; i < NN; ++i) {
                unsigned int m = msk[i];
                if (!m) continue;
                const float qv = qrow[i];
                while (m) {
                    const int jj = __ffs(m) - 1; m &= m - 1;
                    const float* wr = W_mid + (size_t)(i * NN + jj) * HID;
                    for (int cc = tid; cc < HID; cc += 128)
                        h2[cc] = fmaf(qv, wr[cc], h2[cc]);
                }
            }
            __syncthreads();
            for (int cc = tid; cc < HID; cc += 128) h2[cc] = fmaxf(h2[cc], 0.f);
            __syncthreads();
            if (tid < KVQ) {
                const int sel = tid >> 5, nn = tid & 31;
                const float* W2 = sel == 0 ? Wk2 : sel == 1 ? Wv2 : Wq2;
                float a2 = (sel == 0 ? bk2 : sel == 1 ? bv2 : bq2)[nn];
                for (int cc = 0; cc < HID; ++cc)
                    a2 = fmaf(h2[cc], W2[cc * NN + nn], a2);
                if (sel == 2) a2 = sigmoidf_(a2);
                obase[d * KVQ + tid] = a2;
                if (tid < 64) kt2[d * 64 + tid] = a2;
            }
            __syncthreads();
        }
    }
    __syncthreads();
    float p[8], am[8];
    #pragma unroll
    for (int r = 0; r < 8; ++r) { p[r] = 0.f; am[r] = 0.f; }
    for (int tt = 0; tt < 16; ++tt) {
        float4 k0[4], k1[4]; float vv[4];
        #pragma unroll
        for (int d2 = 0; d2 < 4; ++d2) {
            const int t = tt * 4 + d2;
            k0[d2] = *(const float4*)&kt2[t * 64 + i0];
            k1[d2] = *(const float4*)&kt2[t * 64 + i0 + 4];
            vv[d2] = kt2[t * 64 + 32 + j];
        }
        #pragma unroll
        for (int d2 = 0; d2 < 4; ++d2) {
            const float kf[8] = {k0[d2].x, k0[d2].y, k0[d2].z, k0[d2].w,
                                 k1[d2].x, k1[d2].y, k1[d2].z, k1[d2].w};
            #pragma unroll
            for (int r = 0; r < 8; ++r) {
                p[r] = fmaf(0.9f, p[r], kf[r] * vv[d2]);
                am[r] = fmaxf(am[r], fabsf(p[r]));
            }
        }
    }
    #pragma unroll
    for (int r = 0; r < 8; ++r) {
        S2[o2 + (i0 + r) * 32 + j] = p[r];
        P2[o2 + (i0 + r) * 32 + j] = am[r];
    }
}

// ---------------------------------------------------------------- out
__global__ __launch_bounds__(256) void out_kernel(
    const unsigned int* __restrict__ rowany2, const unsigned int* __restrict__ dmask2,
    const float* __restrict__ kvq2,
    const float* __restrict__ W_out, const float* __restrict__ b_out,
    float* __restrict__ y)
{
    const int blk = blockIdx.x;
    const int b = blk >> 2, tq = blk & 3;
    const int tid = threadIdx.x;
    const int wave = tid >> 6, lane = tid & 63;
    const int wg = tq * 4 + wave;
    __shared__ unsigned int mskws[4][NN];
    const int g16 = lane & 15;
    const float4 bo = ((const float4*)b_out)[g16];
    const float4 sy = make_float4(sigmoidf_(bo.x), sigmoidf_(bo.y),
                                  sigmoidf_(bo.z), sigmoidf_(bo.w));
    const unsigned int or4 = rowany2[(b * 4 + 0) * 16 + wg]
                           | rowany2[(b * 4 + 1) * 16 + wg]
                           | rowany2[(b * 4 + 2) * 16 + wg]
                           | rowany2[(b * 4 + 3) * 16 + wg];
    if (or4 == 0) {
        #pragma unroll
        for (int d = 0; d < 32; d += 4) {
            const int t = wg * 32 + d + (lane >> 4);
            ((float4*)(y + ((size_t)t * 64 + b) * OUTW))[g16] = sy;
        }
        return;
    }
    for (int d = 0; d < 32; ++d) {
        const int t = wg * 32 + d;
        float* yr = y + ((size_t)t * 64 + b) * OUTW;
        if (!((or4 >> d) & 1u)) {
            if (lane < 16) ((float4*)yr)[lane] = sy;
            continue;
        }
        const unsigned int* dmw = dmask2 + (size_t)(wg * 64 + b) * 1024;
        for (int i2 = 0; i2 < NN; i2 += 2) {
            const int i = i2 + (lane >> 5), jj = lane & 31;
            const unsigned int wbits = dmw[i * 32 + jj];
            const unsigned long long bal = __ballot(((wbits >> d) & 1u) != 0);
            if (lane == 0)  mskws[wave][i2] = (unsigned int)bal;
            if (lane == 32) mskws[wave][i2 + 1] = (unsigned int)(bal >> 32);
        }
        const float* qrow = kvq2 + ((size_t)b * T_STEPS + t) * KVQ + 2 * NN;
        float a = b_out[lane];
        for (int i = 0; i < NN; ++i) {
            unsigned int m = mskws[wave][i];
            if (!m) continue;
            const float qv = qrow[i];
            while (m) {
                const int jj = __ffs(m) - 1; m &= m - 1;
                a = fmaf(qv, W_out[(size_t)(i * NN + jj) * OUTW + lane], a);
            }
        }
        yr[lane] = sigmoidf_(a);
    }
}

// ---------------------------------------------------------------- launch
extern "C" void kernel_launch(void* const* d_in, const int* in_sizes, int n_in,
                              void* d_out, int out_size, void* d_ws, size_t ws_size,
                              hipStream_t stream)
{
    const float* x     = (const float*)d_in[0];
    const float* W_in  = (const float*)d_in[1];
    const float* b_in  = (const float*)d_in[2];
    const float* Wk1   = (const float*)d_in[3];
    const float* bk1   = (const float*)d_in[4];
    const float* Wv1   = (const float*)d_in[5];
    const float* bv1   = (const float*)d_in[6];
    const float* Wq1   = (const float*)d_in[7];
    const float* bq1   = (const float*)d_in[8];
    const float* W_mid = (const float*)d_in[9];
    const float* b_mid = (const float*)d_in[10];
    const float* Wk2   = (const float*)d_in[11];
    const float* bk2   = (const float*)d_in[12];
    const float* Wv2   = (const float*)d_in[13];
    const float* bv2   = (const float*)d_in[14];
    const float* Wq2   = (const float*)d_in[15];
    const float* bq2   = (const float*)d_in[16];
    const float* W_out = (const float*)d_in[17];
    const float* b_out = (const float*)d_in[18];
    float* y = (float*)d_out;

    float* ws = (float*)d_ws;
    float* W1eff  = ws;                                 // 6240
    float* b1eff  = ws + 6240;
    float* const2 = ws + 6336;                          // pad to 8192
    float* kvq1   = ws + 8192;                          // 3,145,728 (b-major)
    float* kvq2   = kvq1 + 3145728;                     // 3,145,728 (b-major)
    unsigned int* dmask1  = (unsigned int*)(kvq2 + 3145728);   // 1,048,576
    unsigned int* dmask2  = dmask1 + 1048576;                  // 1,048,576
    unsigned int* rowany1 = dmask2 + 1048576;                  // 4096
    unsigned int* rowany2 = rowany1 + 4096;                    // 4096
    float* S1 = (float*)(rowany2 + 4096);               // 524,288
    float* P1 = S1 + 524288;
    float* S2 = P1 + 524288;
    float* P2 = S2 + 524288;

    prep_kernel<<<INW + 2, 512, 0, stream>>>(W_in, b_in, Wk1, bk1, Wv1, bv1, Wq1, bq1,
                                             b_mid, Wk2, bk2, Wv2, bv2, Wq2, bq2,
                                             W1eff, b1eff, const2);
    kvq1p1_kernel<<<BATCH * 8, 128, 0, stream>>>(x, W1eff, b1eff, kvq1, S1, P1);
    cc_kernel<<<BATCH, 256, 0, stream>>>(S1, P1, kvq1, rowany1, dmask1);
    midp1_kernel<<<BATCH * 8, 128, 0, stream>>>(rowany1, dmask1, kvq1, W_mid, b_mid,
                                                Wk2, bk2, Wv2, bv2, Wq2, bq2,
                                                const2, kvq2, S2, P2);
    cc_kernel<<<BATCH, 256, 0, stream>>>(S2, P2, kvq2, rowany2, dmask2);
    out_kernel<<<BATCH * 4, 256, 0, stream>>>(rowany2, dmask2, kvq2, W_out, b_out, y);
}

// Round 8
// 147.645 us; speedup vs baseline: 4.2582x; 1.0291x over previous
//
#include <hip/hip_runtime.h>
#include <math.h>

// Gen2AssocModel forward. T=512, B=64, N=32, HID=1024, SEQ_WIDTH=64.
// 6 dispatches. Hot path (no spikes) traffic-minimized:
//   prep:    W1eff = W_in @ [Wk1|Wv1|Wq1] (65x96), b1eff, const2.
//   kvq1p1:  per (b,seg=64t): GEMM tile -> LDS -> kvq1, phase1 from LDS,
//            block-reduced to 2 scalars cert1[b,seg] = (max|S|, max P).
//   cc:      per b: scalar cert chain; clean -> rowany=0 (16 KB total);
//            dirty -> EXACT serial replay (with const2 row substitution for
//            layer 2) -> dmask+rowany.
//   mid:     per (b,seg): clean -> RETURN (nothing consumes const rows);
//            mixed -> exact dirty rows -> kvq2 + tile phase1 -> cert2 scalars.
//   cc(2):   clean segs use CLOSED-FORM cert scalars from const2
//            (s = max|c2k|*max|c2v|*G64, monotone ramp); mixed read cert2.
//   out:     rowany2 fast path -> sigmoid(b_out); sparse cold substitutes
//            const2 q-row for layer-1-clean rows.
// Workspace ~32 MB.

#define T_STEPS 512
#define BATCH   64
#define NN      32
#define HID     1024
#define INW     65
#define OUTW    64
#define KVQ     96

__device__ __forceinline__ float sigmoidf_(float x) { return 1.0f / (1.0f + expf(-x)); }

// ---------------------------------------------------------------- prep
__global__ __launch_bounds__(512) void prep_kernel(
    const float* __restrict__ W_in, const float* __restrict__ b_in,
    const float* __restrict__ Wk1, const float* __restrict__ bk1,
    const float* __restrict__ Wv1, const float* __restrict__ bv1,
    const float* __restrict__ Wq1, const float* __restrict__ bq1,
    const float* __restrict__ b_mid,
    const float* __restrict__ Wk2, const float* __restrict__ bk2,
    const float* __restrict__ Wv2, const float* __restrict__ bv2,
    const float* __restrict__ Wq2, const float* __restrict__ bq2,
    float* __restrict__ W1eff, float* __restrict__ b1eff,
    float* __restrict__ const2)
{
    const int m = blockIdx.x;                 // 0..66
    const int tid = threadIdx.x;
    __shared__ float srcv[HID];
    __shared__ float part[512];
    for (int h = tid; h < HID; h += 512) {
        float s;
        if (m < INW)       s = W_in[m * HID + h];
        else if (m == INW) s = b_in[h];
        else               s = fmaxf(b_mid[h], 0.f);
        srcv[h] = s;
    }
    __syncthreads();
    const int hq = tid >> 7, ns = tid & 127;  // ns<96 active
    const int sel = ns >> 5, nn = ns & 31;
    const bool layer2 = (m == INW + 1);
    const float* W = layer2 ? (sel == 0 ? Wk2 : sel == 1 ? Wv2 : Wq2)
                            : (sel == 0 ? Wk1 : sel == 1 ? Wv1 : Wq1);
    float acc = 0.f;
    if (ns < KVQ) {
        const int h0 = hq * 256;
        #pragma unroll 8
        for (int hh = 0; hh < 256; ++hh)
            acc = fmaf(srcv[h0 + hh], W[(h0 + hh) * NN + nn], acc);
    }
    part[tid] = acc;
    __syncthreads();
    if (hq == 0 && ns < KVQ) {
        float tot = part[ns] + part[128 + ns] + part[256 + ns] + part[384 + ns];
        if (m < INW) {
            W1eff[m * KVQ + ns] = tot;
        } else if (m == INW) {
            tot += (sel == 0 ? bk1 : sel == 1 ? bv1 : bq1)[nn];
            b1eff[ns] = tot;
        } else {
            tot += (sel == 0 ? bk2 : sel == 1 ? bv2 : bq2)[nn];
            const2[ns] = (sel == 2) ? sigmoidf_(tot) : tot;
        }
    }
}

// ---------------------------------------------------------------- kvq1 + phase1
// grid 512 = b*8+seg, block 128. GEMM tile in LDS -> kvq1 global; phase1 on
// the LDS tile; block-reduce (max|S|, max P) -> cert1[(b*8+seg)*2].
__global__ __launch_bounds__(128) void kvq1p1_kernel(
    const float* __restrict__ x, const float* __restrict__ W1eff,
    const float* __restrict__ b1eff, float* __restrict__ kvq1,
    float* __restrict__ cert1)
{
    const int b = blockIdx.x >> 3, seg = blockIdx.x & 7;
    const int tid = threadIdx.x;
    __shared__ __align__(16) float Ws[INW * KVQ];   // 24.4 KB
    __shared__ __align__(16) float bs[KVQ];
    __shared__ __align__(16) float pool[64 * 100];  // 25.6 KB: xsT then kt
    __shared__ float red[4];
    for (int i4 = tid; i4 < (INW * KVQ) / 4; i4 += 128)
        ((float4*)Ws)[i4] = ((const float4*)W1eff)[i4];
    if (tid < KVQ) bs[tid] = b1eff[tid];
    for (int l = tid; l < 64 * INW; l += 128) {
        const int r = l / INW, m = l - r * INW;
        pool[m * 68 + r] = x[((size_t)((seg * 64 + r) * 64 + b)) * INW + m];
    }
    __syncthreads();
    const int rg = tid >> 3;          // rows rg*4..+4
    const int c0 = (tid & 7) * 12;    // cols c0..+12
    float acc[4][12];
    #pragma unroll
    for (int r = 0; r < 4; ++r)
        #pragma unroll
        for (int k = 0; k < 12; ++k) acc[r][k] = bs[c0 + k];
    #pragma unroll 5
    for (int m = 0; m < INW; ++m) {
        const float4 xv = *(const float4*)&pool[m * 68 + rg * 4];
        const float4 w0 = *(const float4*)&Ws[m * KVQ + c0];
        const float4 w1 = *(const float4*)&Ws[m * KVQ + c0 + 4];
        const float4 w2 = *(const float4*)&Ws[m * KVQ + c0 + 8];
        const float xr[4] = {xv.x, xv.y, xv.z, xv.w};
        const float wk[12] = {w0.x, w0.y, w0.z, w0.w, w1.x, w1.y, w1.z, w1.w,
                              w2.x, w2.y, w2.z, w2.w};
        #pragma unroll
        for (int r = 0; r < 4; ++r)
            #pragma unroll
            for (int k = 0; k < 12; ++k)
                acc[r][k] = fmaf(xr[r], wk[k], acc[r][k]);
    }
    __syncthreads();   // xsT dead; pool becomes kt[row*100 + col]
    #pragma unroll
    for (int r = 0; r < 4; ++r) {
        const int row = rg * 4 + r;
        float v[12];
        #pragma unroll
        for (int k = 0; k < 12; ++k)
            v[k] = (c0 + k >= 2 * NN) ? sigmoidf_(acc[r][k]) : acc[r][k];
        float* kt = &pool[row * 100 + c0];
        *(float4*)&kt[0] = make_float4(v[0], v[1], v[2], v[3]);
        *(float4*)&kt[4] = make_float4(v[4], v[5], v[6], v[7]);
        *(float4*)&kt[8] = make_float4(v[8], v[9], v[10], v[11]);
        float* o = kvq1 + ((size_t)b * T_STEPS + seg * 64 + row) * KVQ + c0;
        *(float4*)&o[0] = make_float4(v[0], v[1], v[2], v[3]);
        *(float4*)&o[4] = make_float4(v[4], v[5], v[6], v[7]);
        *(float4*)&o[8] = make_float4(v[8], v[9], v[10], v[11]);
    }
    __syncthreads();
    const int i0 = (tid >> 5) * 8, j = tid & 31;
    float p[8], am[8];
    #pragma unroll
    for (int r = 0; r < 8; ++r) { p[r] = 0.f; am[r] = 0.f; }
    for (int tt = 0; tt < 16; ++tt) {
        float4 k0[4], k1[4]; float vv[4];
        #pragma unroll
        for (int d2 = 0; d2 < 4; ++d2) {
            const int t = tt * 4 + d2;
            k0[d2] = *(const float4*)&pool[t * 100 + i0];
            k1[d2] = *(const float4*)&pool[t * 100 + i0 + 4];
            vv[d2] = pool[t * 100 + 32 + j];
        }
        #pragma unroll
        for (int d2 = 0; d2 < 4; ++d2) {
            const float kf[8] = {k0[d2].x, k0[d2].y, k0[d2].z, k0[d2].w,
                                 k1[d2].x, k1[d2].y, k1[d2].z, k1[d2].w};
            #pragma unroll
            for (int r = 0; r < 8; ++r) {
                p[r] = fmaf(0.9f, p[r], kf[r] * vv[d2]);
                am[r] = fmaxf(am[r], fabsf(p[r]));
            }
        }
    }
    float ls = 0.f, lp = 0.f;
    #pragma unroll
    for (int r = 0; r < 8; ++r) { ls = fmaxf(ls, fabsf(p[r])); lp = fmaxf(lp, am[r]); }
    #pragma unroll
    for (int off = 32; off; off >>= 1) {
        ls = fmaxf(ls, __shfl_xor(ls, off));
        lp = fmaxf(lp, __shfl_xor(lp, off));
    }
    const int lane = tid & 63, wv = tid >> 6;
    if (lane == 0) { red[wv * 2] = ls; red[wv * 2 + 1] = lp; }
    __syncthreads();
    if (tid == 0) {
        cert1[blockIdx.x * 2 + 0] = fmaxf(red[0], red[2]);
        cert1[blockIdx.x * 2 + 1] = fmaxf(red[1], red[3]);
    }
}

// ---------------------------------------------------------------- cc (cert + cleanup)
// grid 64 (per b), block 256. Hot: scalar cert chain Mb = c64*Mb + smax,
// ub = Mb + pmax <= 0.999 (conservative upper bound; margin >> fp error).
// Layer 2 (cdef!=null): clean segs (per rowany_prev) use closed-form scalar
// s = max|c2k|*max|c2v|*G64 (monotone ramp => pmax = s). Dirty -> EXACT
// serial replay; layer-2 rows never written substitute const2 via rowany_prev.
__global__ __launch_bounds__(256) void cc_kernel(
    const float* __restrict__ cert, const float* __restrict__ kvq,
    unsigned int* __restrict__ rowany, unsigned int* __restrict__ dmask,
    const unsigned int* __restrict__ rowany_prev, const float* __restrict__ cdef)
{
    const int b = blockIdx.x;
    const int tid = threadIdx.x;
    const float c64 = 0.0011790184577738599f;   // 0.9^64
    const float G64 = 9.988209815422261f;       // (1-0.9^64)/0.1
    __shared__ __align__(16) float c2l[64];
    float scs = 0.f;
    if (cdef) {
        if (tid < 64) c2l[tid] = cdef[tid];
        __syncthreads();
        float mk = 0.f, mv = 0.f;
        #pragma unroll 8
        for (int i = 0; i < 32; ++i) {
            mk = fmaxf(mk, fabsf(c2l[i]));
            mv = fmaxf(mv, fabsf(c2l[32 + i]));
        }
        scs = mk * mv * G64;
    }
    float Mb = 0.f;
    bool fl = false;
    #pragma unroll
    for (int g = 0; g < 8; ++g) {
        bool mixed = true;
        if (rowany_prev) {
            unsigned int m = 0u;
            #pragma unroll
            for (int iq = 0; iq < 4; ++iq)
                m |= rowany_prev[(b * 4 + iq) * 16 + 2 * g]
                   | rowany_prev[(b * 4 + iq) * 16 + 2 * g + 1];
            mixed = (m != 0u);
        }
        float smax, pmax;
        if (mixed) { smax = cert[(b * 8 + g) * 2]; pmax = cert[(b * 8 + g) * 2 + 1]; }
        else       { smax = scs; pmax = scs; }
        const float ub = Mb + pmax;              // Mb >= 0 by construction
        fl |= !(ub * 1.0001f <= 0.999f);
        Mb = fmaf(c64, Mb, smax);
    }
    if (!fl) {
        if (tid < 64) rowany[b * 64 + tid] = 0u;
        return;
    }
    // ---- cold: exact serial replay ----
    __shared__ float buf[64 * 64];   // 16 KB: [dt][k(32)|v(32)]
    const int j = tid & 31, ig = tid >> 5;   // membranes i = ig*4..+4
    const int wavei = tid >> 6;
    float mem[4] = {0.f, 0.f, 0.f, 0.f};
    unsigned int u[4] = {0u, 0u, 0u, 0u};
    for (int c = 0; c < 8; ++c) {
        unsigned int orA = 0xFFFFFFFFu, orB = 0xFFFFFFFFu;
        if (rowany_prev) {
            orA = 0u; orB = 0u;
            #pragma unroll
            for (int iq = 0; iq < 4; ++iq) {
                orA |= rowany_prev[(b * 4 + iq) * 16 + 2 * c];
                orB |= rowany_prev[(b * 4 + iq) * 16 + 2 * c + 1];
            }
        }
        __syncthreads();
        #pragma unroll
        for (int r = 0; r < 4; ++r) {
            const int s4 = tid + 256 * r;          // 1024 float4 slots
            const int dt = s4 >> 4, q = s4 & 15;   // cols 0..63 = k|v
            const unsigned int orw = (dt < 32) ? orA : orB;
            float4 val;
            if (rowany_prev && !((orw >> (dt & 31)) & 1u))
                val = *(const float4*)&c2l[q * 4];
            else
                val = *(const float4*)(kvq + ((size_t)b * T_STEPS + c * 64 + dt) * KVQ + q * 4);
            *(float4*)&buf[dt * 64 + q * 4] = val;
        }
        __syncthreads();
        for (int dt = 0; dt < 64; ++dt) {
            const float4 kk = *(const float4*)&buf[dt * 64 + ig * 4];
            const float vv = buf[dt * 64 + 32 + j];
            const float kf[4] = {kk.x, kk.y, kk.z, kk.w};
            #pragma unroll
            for (int r = 0; r < 4; ++r) {
                mem[r] = fmaf(0.9f, mem[r], kf[r] * vv);
                const bool s = mem[r] > 1.f; if (s) mem[r] -= 1.f;
                u[r] |= (s ? 1u : 0u) << (dt & 31);
            }
            if ((dt & 31) == 31) {
                const int wg = c * 2 + (dt >> 5);
                unsigned int* dm = dmask + (size_t)(wg * 64 + b) * 1024;
                unsigned int a = 0;
                #pragma unroll
                for (int r = 0; r < 4; ++r) {
                    dm[(ig * 4 + r) * 32 + j] = u[r];
                    a |= u[r]; u[r] = 0u;
                }
                #pragma unroll
                for (int off = 32; off; off >>= 1) a |= __shfl_xor(a, off);
                if ((tid & 63) == 0) rowany[(b * 4 + wavei) * 16 + wg] = a;
            }
        }
    }
}

// ---------------------------------------------------------------- mid (sparse only)
// grid 512 = b*8+seg, block 128. Clean -> immediate return (nothing consumes
// const rows). Mixed: exact rows for dirty t -> kvq2; tile phase1 -> cert2.
__global__ __launch_bounds__(128) void mid_kernel(
    const unsigned int* __restrict__ rowany1, const unsigned int* __restrict__ dmask1,
    const float* __restrict__ kvq1,
    const float* __restrict__ W_mid, const float* __restrict__ b_mid,
    const float* __restrict__ Wk2, const float* __restrict__ bk2,
    const float* __restrict__ Wv2, const float* __restrict__ bv2,
    const float* __restrict__ Wq2, const float* __restrict__ bq2,
    const float* __restrict__ const2, float* __restrict__ kvq2,
    float* __restrict__ cert2)
{
    const int b = blockIdx.x >> 3, seg = blockIdx.x & 7;
    const int tid = threadIdx.x;
    const int w0 = seg * 2;
    const unsigned int orA = rowany1[(b * 4 + 0) * 16 + w0] | rowany1[(b * 4 + 1) * 16 + w0]
                           | rowany1[(b * 4 + 2) * 16 + w0] | rowany1[(b * 4 + 3) * 16 + w0];
    const unsigned int orB = rowany1[(b * 4 + 0) * 16 + w0 + 1] | rowany1[(b * 4 + 1) * 16 + w0 + 1]
                           | rowany1[(b * 4 + 2) * 16 + w0 + 1] | rowany1[(b * 4 + 3) * 16 + w0 + 1];
    if ((orA | orB) == 0u) return;
    // ---- mixed (cold) ----
    __shared__ __align__(16) float c2s[KVQ];
    __shared__ __align__(16) float kt2[64 * 64];   // 16 KB (k,v)
    __shared__ float h2[HID];
    __shared__ unsigned int msk[NN];
    __shared__ float red[4];
    if (tid < KVQ) c2s[tid] = const2[tid];
    __syncthreads();
    float* obase = kvq2 + ((size_t)b * T_STEPS + seg * 64) * KVQ;
    for (int d = 0; d < 64; ++d) {
        const unsigned int orw = (d < 32) ? orA : orB;
        const int bit = d & 31;
        if (!((orw >> bit) & 1u)) {
            if (tid < 16) *(float4*)&kt2[d * 64 + tid * 4] = ((const float4*)c2s)[tid];
        } else {
            const int wg = w0 + (d >> 5);
            const unsigned int* dmw = dmask1 + (size_t)(wg * 64 + b) * 1024;
            for (int i2 = 0; i2 < NN; i2 += 4) {
                const int i = i2 + (tid >> 5);
                const unsigned int wb = dmw[i * 32 + (tid & 31)];
                const unsigned long long balm = __ballot(((wb >> bit) & 1u) != 0);
                const int ibase = i2 + (tid >> 6) * 2;
                if ((tid & 63) == 0)  msk[ibase]     = (unsigned int)balm;
                if ((tid & 63) == 32) msk[ibase + 1] = (unsigned int)(balm >> 32);
            }
            for (int cc = tid; cc < HID; cc += 128) h2[cc] = b_mid[cc];
            __syncthreads();
            const float* qrow = kvq1 + ((size_t)b * T_STEPS + seg * 64 + d) * KVQ + 2 * NN;
            for (int i = 0; i < NN; ++i) {
                unsigned int m = msk[i];
                if (!m) continue;
                const float qv = qrow[i];
                while (m) {
                    const int jj = __ffs(m) - 1; m &= m - 1;
                    const float* wr = W_mid + (size_t)(i * NN + jj) * HID;
                    for (int cc = tid; cc < HID; cc += 128)
                        h2[cc] = fmaf(qv, wr[cc], h2[cc]);
                }
            }
            __syncthreads();
            for (int cc = tid; cc < HID; cc += 128) h2[cc] = fmaxf(h2[cc], 0.f);
            __syncthreads();
            if (tid < KVQ) {
                const int sel = tid >> 5, nn = tid & 31;
                const float* W2 = sel == 0 ? Wk2 : sel == 1 ? Wv2 : Wq2;
                float a2 = (sel == 0 ? bk2 : sel == 1 ? bv2 : bq2)[nn];
                for (int cc = 0; cc < HID; ++cc)
                    a2 = fmaf(h2[cc], W2[cc * NN + nn], a2);
                if (sel == 2) a2 = sigmoidf_(a2);
                obase[d * KVQ + tid] = a2;
                if (tid < 64) kt2[d * 64 + tid] = a2;
            }
            __syncthreads();
        }
    }
    __syncthreads();
    const int i0 = (tid >> 5) * 8, j = tid & 31;
    float p[8], am[8];
    #pragma unroll
    for (int r = 0; r < 8; ++r) { p[r] = 0.f; am[r] = 0.f; }
    for (int tt = 0; tt < 16; ++tt) {
        float4 k0[4], k1[4]; float vv[4];
        #pragma unroll
        for (int d2 = 0; d2 < 4; ++d2) {
            const int t = tt * 4 + d2;
            k0[d2] = *(const float4*)&kt2[t * 64 + i0];
            k1[d2] = *(const float4*)&kt2[t * 64 + i0 + 4];
            vv[d2] = kt2[t * 64 + 32 + j];
        }
        #pragma unroll
        for (int d2 = 0; d2 < 4; ++d2) {
            const float kf[8] = {k0[d2].x, k0[d2].y, k0[d2].z, k0[d2].w,
                                 k1[d2].x, k1[d2].y, k1[d2].z, k1[d2].w};
            #pragma unroll
            for (int r = 0; r < 8; ++r) {
                p[r] = fmaf(0.9f, p[r], kf[r] * vv[d2]);
                am[r] = fmaxf(am[r], fabsf(p[r]));
            }
        }
    }
    float ls = 0.f, lp = 0.f;
    #pragma unroll
    for (int r = 0; r < 8; ++r) { ls = fmaxf(ls, fabsf(p[r])); lp = fmaxf(lp, am[r]); }
    #pragma unroll
    for (int off = 32; off; off >>= 1) {
        ls = fmaxf(ls, __shfl_xor(ls, off));
        lp = fmaxf(lp, __shfl_xor(lp, off));
    }
    const int lane = tid & 63, wv = tid >> 6;
    if (lane == 0) { red[wv * 2] = ls; red[wv * 2 + 1] = lp; }
    __syncthreads();
    if (tid == 0) {
        cert2[blockIdx.x * 2 + 0] = fmaxf(red[0], red[2]);
        cert2[blockIdx.x * 2 + 1] = fmaxf(red[1], red[3]);
    }
}

// ---------------------------------------------------------------- out
__global__ __launch_bounds__(256) void out_kernel(
    const unsigned int* __restrict__ rowany2, const unsigned int* __restrict__ dmask2,
    const unsigned int* __restrict__ rowany1,
    const float* __restrict__ kvq2, const float* __restrict__ const2,
    const float* __restrict__ W_out, const float* __restrict__ b_out,
    float* __restrict__ y)
{
    const int blk = blockIdx.x;
    const int b = blk >> 2, tq = blk & 3;
    const int tid = threadIdx.x;
    const int wave = tid >> 6, lane = tid & 63;
    const int wg = tq * 4 + wave;
    __shared__ unsigned int mskws[4][NN];
    const int g16 = lane & 15;
    const float4 bo = ((const float4*)b_out)[g16];
    const float4 sy = make_float4(sigmoidf_(bo.x), sigmoidf_(bo.y),
                                  sigmoidf_(bo.z), sigmoidf_(bo.w));
    const unsigned int or4 = rowany2[(b * 4 + 0) * 16 + wg]
                           | rowany2[(b * 4 + 1) * 16 + wg]
                           | rowany2[(b * 4 + 2) * 16 + wg]
                           | rowany2[(b * 4 + 3) * 16 + wg];
    if (or4 == 0) {
        #pragma unroll
        for (int d = 0; d < 32; d += 4) {
            const int t = wg * 32 + d + (lane >> 4);
            ((float4*)(y + ((size_t)t * 64 + b) * OUTW))[g16] = sy;
        }
        return;
    }
    // layer-1 dirtiness of rows in this window (for kvq2 substitution)
    const unsigned int or1 = rowany1[(b * 4 + 0) * 16 + wg]
                           | rowany1[(b * 4 + 1) * 16 + wg]
                           | rowany1[(b * 4 + 2) * 16 + wg]
                           | rowany1[(b * 4 + 3) * 16 + wg];
    for (int d = 0; d < 32; ++d) {
        const int t = wg * 32 + d;
        float* yr = y + ((size_t)t * 64 + b) * OUTW;
        if (!((or4 >> d) & 1u)) {
            if (lane < 16) ((float4*)yr)[lane] = sy;
            continue;
        }
        const unsigned int* dmw = dmask2 + (size_t)(wg * 64 + b) * 1024;
        for (int i2 = 0; i2 < NN; i2 += 2) {
            const int i = i2 + (lane >> 5), jj = lane & 31;
            const unsigned int wbits = dmw[i * 32 + jj];
            const unsigned long long bal = __ballot(((wbits >> d) & 1u) != 0);
            if (lane == 0)  mskws[wave][i2] = (unsigned int)bal;
            if (lane == 32) mskws[wave][i2 + 1] = (unsigned int)(bal >> 32);
        }
        const float* qrow = ((or1 >> d) & 1u)
            ? kvq2 + ((size_t)b * T_STEPS + t) * KVQ + 2 * NN
            : const2 + 2 * NN;
        float a = b_out[lane];
        for (int i = 0; i < NN; ++i) {
            unsigned int m = mskws[wave][i];
            if (!m) continue;
            const float qv = qrow[i];
            while (m) {
                const int jj = __ffs(m) - 1; m &= m - 1;
                a = fmaf(qv, W_out[(size_t)(i * NN + jj) * OUTW + lane], a);
            }
        }
        yr[lane] = sigmoidf_(a);
    }
}

// ---------------------------------------------------------------- launch
extern "C" void kernel_launch(void* const* d_in, const int* in_sizes, int n_in,
                              void* d_out, int out_size, void* d_ws, size_t ws_size,
                              hipStream_t stream)
{
    const float* x     = (const float*)d_in[0];
    const float* W_in  = (const float*)d_in[1];
    const float* b_in  = (const float*)d_in[2];
    const float* Wk1   = (const float*)d_in[3];
    const float* bk1   = (const float*)d_in[4];
    const float* Wv1   = (const float*)d_in[5];
    const float* bv1   = (const float*)d_in[6];
    const float* Wq1   = (const float*)d_in[7];
    const float* bq1   = (const float*)d_in[8];
    const float* W_mid = (const float*)d_in[9];
    const float* b_mid = (const float*)d_in[10];
    const float* Wk2   = (const float*)d_in[11];
    const float* bk2   = (const float*)d_in[12];
    const float* Wv2   = (const float*)d_in[13];
    const float* bv2   = (const float*)d_in[14];
    const float* Wq2   = (const float*)d_in[15];
    const float* bq2   = (const float*)d_in[16];
    const float* W_out = (const float*)d_in[17];
    const float* b_out = (const float*)d_in[18];
    float* y = (float*)d_out;

    float* ws = (float*)d_ws;
    float* W1eff  = ws;                                 // 6240
    float* b1eff  = ws + 6240;
    float* const2 = ws + 6336;                          // pad to 8192
    float* kvq1   = ws + 8192;                          // 3,145,728 (b-major)
    float* kvq2   = kvq1 + 3145728;                     // 3,145,728 (b-major)
    unsigned int* dmask1  = (unsigned int*)(kvq2 + 3145728);   // 1,048,576
    unsigned int* dmask2  = dmask1 + 1048576;                  // 1,048,576
    unsigned int* rowany1 = dmask2 + 1048576;                  // 4096
    unsigned int* rowany2 = rowany1 + 4096;                    // 4096
    float* cert1 = (float*)(rowany2 + 4096);            // 1024
    float* cert2 = cert1 + 1024;                        // 1024

    prep_kernel<<<INW + 2, 512, 0, stream>>>(W_in, b_in, Wk1, bk1, Wv1, bv1, Wq1, bq1,
                                             b_mid, Wk2, bk2, Wv2, bv2, Wq2, bq2,
                                             W1eff, b1eff, const2);
    kvq1p1_kernel<<<BATCH * 8, 128, 0, stream>>>(x, W1eff, b1eff, kvq1, cert1);
    cc_kernel<<<BATCH, 256, 0, stream>>>(cert1, kvq1, rowany1, dmask1,
                                         (const unsigned int*)nullptr,
                                         (const float*)nullptr);
    mid_kernel<<<BATCH * 8, 128, 0, stream>>>(rowany1, dmask1, kvq1, W_mid, b_mid,
                                              Wk2, bk2, Wv2, bv2, Wq2, bq2,
                                              const2, kvq2, cert2);
    cc_kernel<<<BATCH, 256, 0, stream>>>(cert2, kvq2, rowany2, dmask2,
                                         rowany1, const2);
    out_kernel<<<BATCH * 4, 256, 0, stream>>>(rowany2, dmask2, rowany1,
                                              kvq2, const2, W_out, b_out, y);
}

// Round 9
// 141.035 us; speedup vs baseline: 4.4578x; 1.0469x over previous
//
#include <hip/hip_runtime.h>
#include <math.h>

// Gen2AssocModel forward. T=512, B=64, N=32, HID=1024, SEQ_WIDTH=64.
// 7 dispatches. R9: de-fused kvq1p1 (45.8us, 1 wave/SIMD latency-bound) into
// R4's known-good GEMM + a high-occupancy standalone phase1.
//   prep:    W1eff = W_in @ [Wk1|Wv1|Wq1] (65x96), b1eff, const2.
//   kvq1:    (32768x65)@(65x96), 4row x 12col register tiles, float4 LDS.
//   phase1:  per (b,seg=64t): 16KB staged k|v, 4 membranes/thread, register
//            double-buffer; cert1[b,seg] = (max|S|, max P) scalars.
//   cc:      per b: scalar cert chain; clean -> rowany=0; dirty -> EXACT
//            serial replay (const2 row substitution on layer 2).
//   mid:     clean seg -> return; mixed -> exact dirty rows + tile phase1.
//   out:     rowany2 fast path -> sigmoid(b_out); sparse cold exact.
// Workspace ~32 MB.

#define T_STEPS 512
#define BATCH   64
#define NN      32
#define HID     1024
#define INW     65
#define OUTW    64
#define ROWS    (T_STEPS * BATCH)
#define KVQ     96

__device__ __forceinline__ float sigmoidf_(float x) { return 1.0f / (1.0f + expf(-x)); }

// ---------------------------------------------------------------- prep
__global__ __launch_bounds__(512) void prep_kernel(
    const float* __restrict__ W_in, const float* __restrict__ b_in,
    const float* __restrict__ Wk1, const float* __restrict__ bk1,
    const float* __restrict__ Wv1, const float* __restrict__ bv1,
    const float* __restrict__ Wq1, const float* __restrict__ bq1,
    const float* __restrict__ b_mid,
    const float* __restrict__ Wk2, const float* __restrict__ bk2,
    const float* __restrict__ Wv2, const float* __restrict__ bv2,
    const float* __restrict__ Wq2, const float* __restrict__ bq2,
    float* __restrict__ W1eff, float* __restrict__ b1eff,
    float* __restrict__ const2)
{
    const int m = blockIdx.x;                 // 0..66
    const int tid = threadIdx.x;
    __shared__ float srcv[HID];
    __shared__ float part[512];
    for (int h = tid; h < HID; h += 512) {
        float s;
        if (m < INW)       s = W_in[m * HID + h];
        else if (m == INW) s = b_in[h];
        else               s = fmaxf(b_mid[h], 0.f);
        srcv[h] = s;
    }
    __syncthreads();
    const int hq = tid >> 7, ns = tid & 127;  // ns<96 active
    const int sel = ns >> 5, nn = ns & 31;
    const bool layer2 = (m == INW + 1);
    const float* W = layer2 ? (sel == 0 ? Wk2 : sel == 1 ? Wv2 : Wq2)
                            : (sel == 0 ? Wk1 : sel == 1 ? Wv1 : Wq1);
    float acc = 0.f;
    if (ns < KVQ) {
        const int h0 = hq * 256;
        #pragma unroll 8
        for (int hh = 0; hh < 256; ++hh)
            acc = fmaf(srcv[h0 + hh], W[(h0 + hh) * NN + nn], acc);
    }
    part[tid] = acc;
    __syncthreads();
    if (hq == 0 && ns < KVQ) {
        float tot = part[ns] + part[128 + ns] + part[256 + ns] + part[384 + ns];
        if (m < INW) {
            W1eff[m * KVQ + ns] = tot;
        } else if (m == INW) {
            tot += (sel == 0 ? bk1 : sel == 1 ? bv1 : bq1)[nn];
            b1eff[ns] = tot;
        } else {
            tot += (sel == 0 ? bk2 : sel == 1 ? bv2 : bq2)[nn];
            const2[ns] = (sel == 2) ? sigmoidf_(tot) : tot;
        }
    }
}

// ---------------------------------------------------------------- kvq1 (R4 shape, known-good)
// grid 256, block 256. 128 rows/block; thread = 4 rows x 12 cols.
__global__ __launch_bounds__(256) void kvq1_kernel(
    const float* __restrict__ x, const float* __restrict__ W1eff,
    const float* __restrict__ b1eff, float* __restrict__ kvq1)
{
    const int tid = threadIdx.x;
    const int r0 = blockIdx.x * 128;
    __shared__ float Ws[INW * KVQ];        // 24.4 KB
    __shared__ float xsT[INW * 132];       // 34.3 KB  [m][row], pad 132
    __shared__ float bs[KVQ];
    for (int i4 = tid; i4 < (INW * KVQ) / 4; i4 += 256)
        ((float4*)Ws)[i4] = ((const float4*)W1eff)[i4];
    for (int l = tid; l < 128 * INW; l += 256) {
        const int r = l / INW, m = l - r * INW;
        xsT[m * 132 + r] = x[(size_t)(r0 + r) * INW + m];
    }
    if (tid < KVQ) bs[tid] = b1eff[tid];
    __syncthreads();
    const int rg = tid >> 3;          // 0..31 -> rows rg*4..+3
    const int c0 = (tid & 7) * 12;    // cols [c0, c0+12)
    float acc[4][12];
    #pragma unroll
    for (int r = 0; r < 4; ++r)
        #pragma unroll
        for (int k = 0; k < 12; ++k) acc[r][k] = bs[c0 + k];
    for (int m = 0; m < INW; ++m) {
        const float4 xv = *(const float4*)&xsT[m * 132 + rg * 4];
        const float4 w0 = *(const float4*)&Ws[m * KVQ + c0];
        const float4 w1 = *(const float4*)&Ws[m * KVQ + c0 + 4];
        const float4 w2 = *(const float4*)&Ws[m * KVQ + c0 + 8];
        const float xr[4] = {xv.x, xv.y, xv.z, xv.w};
        const float wk[12] = {w0.x, w0.y, w0.z, w0.w, w1.x, w1.y, w1.z, w1.w,
                              w2.x, w2.y, w2.z, w2.w};
        #pragma unroll
        for (int r = 0; r < 4; ++r)
            #pragma unroll
            for (int k = 0; k < 12; ++k)
                acc[r][k] = fmaf(xr[r], wk[k], acc[r][k]);
    }
    #pragma unroll
    for (int r = 0; r < 4; ++r) {
        const int g = r0 + rg * 4 + r;   // = t*64 + b
        const int t = g >> 6, b = g & 63;
        float* o = kvq1 + ((size_t)b * T_STEPS + t) * KVQ + c0;
        float v[12];
        #pragma unroll
        for (int k = 0; k < 12; ++k)
            v[k] = (c0 + k >= 2 * NN) ? sigmoidf_(acc[r][k]) : acc[r][k];
        *(float4*)&o[0] = make_float4(v[0], v[1], v[2], v[3]);
        *(float4*)&o[4] = make_float4(v[4], v[5], v[6], v[7]);
        *(float4*)&o[8] = make_float4(v[8], v[9], v[10], v[11]);
    }
}

// ---------------------------------------------------------------- phase1 (standalone)
// grid 512 = b*8+seg, block 256 (4 waves), 16 KB LDS. 4 membranes/thread
// (i0 = (tid>>5)*4, j = tid&31), register double-buffered 4-step batches.
// Emits cert[(b*8+seg)*2] = max|S|, [..+1] = max P.
__global__ __launch_bounds__(256) void phase1_kernel(
    const float* __restrict__ kvq, float* __restrict__ cert)
{
    const int b = blockIdx.x >> 3, seg = blockIdx.x & 7;
    const int tid = threadIdx.x;
    __shared__ __align__(16) float buf[64 * 64];   // 16 KB: [dt][k(32)|v(32)]
    __shared__ float red[8];
    const float* base = kvq + ((size_t)b * T_STEPS + seg * 64) * KVQ;
    #pragma unroll
    for (int r = 0; r < 4; ++r) {
        const int l4 = tid + 256 * r;          // 0..1023
        const int dt = l4 >> 4, q = l4 & 15;   // cols 0..63 = k|v
        *(float4*)&buf[dt * 64 + q * 4] = *(const float4*)(base + dt * KVQ + q * 4);
    }
    __syncthreads();
    const int i0 = (tid >> 5) * 4, j = tid & 31;
    float p[4] = {0.f, 0.f, 0.f, 0.f};
    float am[4] = {0.f, 0.f, 0.f, 0.f};
    float4 kb[2][4]; float vb[2][4];
    #pragma unroll
    for (int d = 0; d < 4; ++d) {
        kb[0][d] = *(const float4*)&buf[d * 64 + i0];
        vb[0][d] = buf[d * 64 + 32 + j];
    }
    #pragma unroll
    for (int bt = 0; bt < 16; ++bt) {
        const int cb = bt & 1;
        if (bt < 15) {
            #pragma unroll
            for (int d = 0; d < 4; ++d) {
                const int dt = (bt + 1) * 4 + d;
                kb[cb ^ 1][d] = *(const float4*)&buf[dt * 64 + i0];
                vb[cb ^ 1][d] = buf[dt * 64 + 32 + j];
            }
        }
        #pragma unroll
        for (int d = 0; d < 4; ++d) {
            const float vv = vb[cb][d];
            p[0] = fmaf(0.9f, p[0], kb[cb][d].x * vv); am[0] = fmaxf(am[0], fabsf(p[0]));
            p[1] = fmaf(0.9f, p[1], kb[cb][d].y * vv); am[1] = fmaxf(am[1], fabsf(p[1]));
            p[2] = fmaf(0.9f, p[2], kb[cb][d].z * vv); am[2] = fmaxf(am[2], fabsf(p[2]));
            p[3] = fmaf(0.9f, p[3], kb[cb][d].w * vv); am[3] = fmaxf(am[3], fabsf(p[3]));
        }
    }
    float ls = 0.f, lp = 0.f;
    #pragma unroll
    for (int r = 0; r < 4; ++r) { ls = fmaxf(ls, fabsf(p[r])); lp = fmaxf(lp, am[r]); }
    #pragma unroll
    for (int off = 32; off; off >>= 1) {
        ls = fmaxf(ls, __shfl_xor(ls, off));
        lp = fmaxf(lp, __shfl_xor(lp, off));
    }
    const int lane = tid & 63, wv = tid >> 6;
    if (lane == 0) { red[wv * 2] = ls; red[wv * 2 + 1] = lp; }
    __syncthreads();
    if (tid == 0) {
        cert[blockIdx.x * 2 + 0] = fmaxf(fmaxf(red[0], red[2]), fmaxf(red[4], red[6]));
        cert[blockIdx.x * 2 + 1] = fmaxf(fmaxf(red[1], red[3]), fmaxf(red[5], red[7]));
    }
}

// ---------------------------------------------------------------- cc (cert + cleanup)
__global__ __launch_bounds__(256) void cc_kernel(
    const float* __restrict__ cert, const float* __restrict__ kvq,
    unsigned int* __restrict__ rowany, unsigned int* __restrict__ dmask,
    const unsigned int* __restrict__ rowany_prev, const float* __restrict__ cdef)
{
    const int b = blockIdx.x;
    const int tid = threadIdx.x;
    const float c64 = 0.0011790184577738599f;   // 0.9^64
    const float G64 = 9.988209815422261f;       // (1-0.9^64)/0.1
    __shared__ __align__(16) float c2l[64];
    float scs = 0.f;
    if (cdef) {
        if (tid < 64) c2l[tid] = cdef[tid];
        __syncthreads();
        float mk = 0.f, mv = 0.f;
        #pragma unroll 8
        for (int i = 0; i < 32; ++i) {
            mk = fmaxf(mk, fabsf(c2l[i]));
            mv = fmaxf(mv, fabsf(c2l[32 + i]));
        }
        scs = mk * mv * G64;
    }
    float Mb = 0.f;
    bool fl = false;
    #pragma unroll
    for (int g = 0; g < 8; ++g) {
        bool mixed = true;
        if (rowany_prev) {
            unsigned int m = 0u;
            #pragma unroll
            for (int iq = 0; iq < 4; ++iq)
                m |= rowany_prev[(b * 4 + iq) * 16 + 2 * g]
                   | rowany_prev[(b * 4 + iq) * 16 + 2 * g + 1];
            mixed = (m != 0u);
        }
        float smax, pmax;
        if (mixed) { smax = cert[(b * 8 + g) * 2]; pmax = cert[(b * 8 + g) * 2 + 1]; }
        else       { smax = scs; pmax = scs; }
        const float ub = Mb + pmax;              // Mb >= 0 by construction
        fl |= !(ub * 1.0001f <= 0.999f);
        Mb = fmaf(c64, Mb, smax);
    }
    if (!fl) {
        if (tid < 64) rowany[b * 64 + tid] = 0u;
        return;
    }
    // ---- cold: exact serial replay ----
    __shared__ float buf[64 * 64];   // 16 KB: [dt][k(32)|v(32)]
    const int j = tid & 31, ig = tid >> 5;   // membranes i = ig*4..+4
    const int wavei = tid >> 6;
    float mem[4] = {0.f, 0.f, 0.f, 0.f};
    unsigned int u[4] = {0u, 0u, 0u, 0u};
    for (int c = 0; c < 8; ++c) {
        unsigned int orA = 0xFFFFFFFFu, orB = 0xFFFFFFFFu;
        if (rowany_prev) {
            orA = 0u; orB = 0u;
            #pragma unroll
            for (int iq = 0; iq < 4; ++iq) {
                orA |= rowany_prev[(b * 4 + iq) * 16 + 2 * c];
                orB |= rowany_prev[(b * 4 + iq) * 16 + 2 * c + 1];
            }
        }
        __syncthreads();
        #pragma unroll
        for (int r = 0; r < 4; ++r) {
            const int s4 = tid + 256 * r;          // 1024 float4 slots
            const int dt = s4 >> 4, q = s4 & 15;   // cols 0..63 = k|v
            const unsigned int orw = (dt < 32) ? orA : orB;
            float4 val;
            if (rowany_prev && !((orw >> (dt & 31)) & 1u))
                val = *(const float4*)&c2l[q * 4];
            else
                val = *(const float4*)(kvq + ((size_t)b * T_STEPS + c * 64 + dt) * KVQ + q * 4);
            *(float4*)&buf[dt * 64 + q * 4] = val;
        }
        __syncthreads();
        for (int dt = 0; dt < 64; ++dt) {
            const float4 kk = *(const float4*)&buf[dt * 64 + ig * 4];
            const float vv = buf[dt * 64 + 32 + j];
            const float kf[4] = {kk.x, kk.y, kk.z, kk.w};
            #pragma unroll
            for (int r = 0; r < 4; ++r) {
                mem[r] = fmaf(0.9f, mem[r], kf[r] * vv);
                const bool s = mem[r] > 1.f; if (s) mem[r] -= 1.f;
                u[r] |= (s ? 1u : 0u) << (dt & 31);
            }
            if ((dt & 31) == 31) {
                const int wg = c * 2 + (dt >> 5);
                unsigned int* dm = dmask + (size_t)(wg * 64 + b) * 1024;
                unsigned int a = 0;
                #pragma unroll
                for (int r = 0; r < 4; ++r) {
                    dm[(ig * 4 + r) * 32 + j] = u[r];
                    a |= u[r]; u[r] = 0u;
                }
                #pragma unroll
                for (int off = 32; off; off >>= 1) a |= __shfl_xor(a, off);
                if ((tid & 63) == 0) rowany[(b * 4 + wavei) * 16 + wg] = a;
            }
        }
    }
}

// ---------------------------------------------------------------- mid (sparse only)
__global__ __launch_bounds__(128) void mid_kernel(
    const unsigned int* __restrict__ rowany1, const unsigned int* __restrict__ dmask1,
    const float* __restrict__ kvq1,
    const float* __restrict__ W_mid, const float* __restrict__ b_mid,
    const float* __restrict__ Wk2, const float* __restrict__ bk2,
    const float* __restrict__ Wv2, const float* __restrict__ bv2,
    const float* __restrict__ Wq2, const float* __restrict__ bq2,
    const float* __restrict__ const2, float* __restrict__ kvq2,
    float* __restrict__ cert2)
{
    const int b = blockIdx.x >> 3, seg = blockIdx.x & 7;
    const int tid = threadIdx.x;
    const int w0 = seg * 2;
    const unsigned int orA = rowany1[(b * 4 + 0) * 16 + w0] | rowany1[(b * 4 + 1) * 16 + w0]
                           | rowany1[(b * 4 + 2) * 16 + w0] | rowany1[(b * 4 + 3) * 16 + w0];
    const unsigned int orB = rowany1[(b * 4 + 0) * 16 + w0 + 1] | rowany1[(b * 4 + 1) * 16 + w0 + 1]
                           | rowany1[(b * 4 + 2) * 16 + w0 + 1] | rowany1[(b * 4 + 3) * 16 + w0 + 1];
    if ((orA | orB) == 0u) return;
    // ---- mixed (cold) ----
    __shared__ __align__(16) float c2s[KVQ];
    __shared__ __align__(16) float kt2[64 * 64];   // 16 KB (k,v)
    __shared__ float h2[HID];
    __shared__ unsigned int msk[NN];
    __shared__ float red[4];
    if (tid < KVQ) c2s[tid] = const2[tid];
    __syncthreads();
    float* obase = kvq2 + ((size_t)b * T_STEPS + seg * 64) * KVQ;
    for (int d = 0; d < 64; ++d) {
        const unsigned int orw = (d < 32) ? orA : orB;
        const int bit = d & 31;
        if (!((orw >> bit) & 1u)) {
            if (tid < 16) *(float4*)&kt2[d * 64 + tid * 4] = ((const float4*)c2s)[tid];
        } else {
            const int wg = w0 + (d >> 5);
            const unsigned int* dmw = dmask1 + (size_t)(wg * 64 + b) * 1024;
            for (int i2 = 0; i2 < NN; i2 += 4) {
                const int i = i2 + (tid >> 5);
                const unsigned int wb = dmw[i * 32 + (tid & 31)];
                const unsigned long long balm = __ballot(((wb >> bit) & 1u) != 0);
                const int ibase = i2 + (tid >> 6) * 2;
                if ((tid & 63) == 0)  msk[ibase]     = (unsigned int)balm;
                if ((tid & 63) == 32) msk[ibase + 1] = (unsigned int)(balm >> 32);
            }
            for (int cc = tid; cc < HID; cc += 128) h2[cc] = b_mid[cc];
            __syncthreads();
            const float* qrow = kvq1 + ((size_t)b * T_STEPS + seg * 64 + d) * KVQ + 2 * NN;
            for (int i = 0; i < NN; ++i) {
                unsigned int m = msk[i];
                if (!m) continue;
                const float qv = qrow[i];
                while (m) {
                    const int jj = __ffs(m) - 1; m &= m - 1;
                    const float* wr = W_mid + (size_t)(i * NN + jj) * HID;
                    for (int cc = tid; cc < HID; cc += 128)
                        h2[cc] = fmaf(qv, wr[cc], h2[cc]);
                }
            }
            __syncthreads();
            for (int cc = tid; cc < HID; cc += 128) h2[cc] = fmaxf(h2[cc], 0.f);
            __syncthreads();
            if (tid < KVQ) {
                const int sel = tid >> 5, nn = tid & 31;
                const float* W2 = sel == 0 ? Wk2 : sel == 1 ? Wv2 : Wq2;
                float a2 = (sel == 0 ? bk2 : sel == 1 ? bv2 : bq2)[nn];
                for (int cc = 0; cc < HID; ++cc)
                    a2 = fmaf(h2[cc], W2[cc * NN + nn], a2);
                if (sel == 2) a2 = sigmoidf_(a2);
                obase[d * KVQ + tid] = a2;
                if (tid < 64) kt2[d * 64 + tid] = a2;
            }
            __syncthreads();
        }
    }
    __syncthreads();
    const int i0 = (tid >> 5) * 8, j = tid & 31;
    float p[8], am[8];
    #pragma unroll
    for (int r = 0; r < 8; ++r) { p[r] = 0.f; am[r] = 0.f; }
    for (int tt = 0; tt < 16; ++tt) {
        float4 k0[4], k1[4]; float vv[4];
        #pragma unroll
        for (int d2 = 0; d2 < 4; ++d2) {
            const int t = tt * 4 + d2;
            k0[d2] = *(const float4*)&kt2[t * 64 + i0];
            k1[d2] = *(const float4*)&kt2[t * 64 + i0 + 4];
            vv[d2] = kt2[t * 64 + 32 + j];
        }
        #pragma unroll
        for (int d2 = 0; d2 < 4; ++d2) {
            const float kf[8] = {k0[d2].x, k0[d2].y, k0[d2].z, k0[d2].w,
                                 k1[d2].x, k1[d2].y, k1[d2].z, k1[d2].w};
            #pragma unroll
            for (int r = 0; r < 8; ++r) {
                p[r] = fmaf(0.9f, p[r], kf[r] * vv[d2]);
                am[r] = fmaxf(am[r], fabsf(p[r]));
            }
        }
    }
    float ls = 0.f, lp = 0.f;
    #pragma unroll
    for (int r = 0; r < 8; ++r) { ls = fmaxf(ls, fabsf(p[r])); lp = fmaxf(lp, am[r]); }
    #pragma unroll
    for (int off = 32; off; off >>= 1) {
        ls = fmaxf(ls, __shfl_xor(ls, off));
        lp = fmaxf(lp, __shfl_xor(lp, off));
    }
    const int lane = tid & 63, wv = tid >> 6;
    if (lane == 0) { red[wv * 2] = ls; red[wv * 2 + 1] = lp; }
    __syncthreads();
    if (tid == 0) {
        cert2[blockIdx.x * 2 + 0] = fmaxf(red[0], red[2]);
        cert2[blockIdx.x * 2 + 1] = fmaxf(red[1], red[3]);
    }
}

// ---------------------------------------------------------------- out
__global__ __launch_bounds__(256) void out_kernel(
    const unsigned int* __restrict__ rowany2, const unsigned int* __restrict__ dmask2,
    const unsigned int* __restrict__ rowany1,
    const float* __restrict__ kvq2, const float* __restrict__ const2,
    const float* __restrict__ W_out, const float* __restrict__ b_out,
    float* __restrict__ y)
{
    const int blk = blockIdx.x;
    const int b = blk >> 2, tq = blk & 3;
    const int tid = threadIdx.x;
    const int wave = tid >> 6, lane = tid & 63;
    const int wg = tq * 4 + wave;
    __shared__ unsigned int mskws[4][NN];
    const int g16 = lane & 15;
    const float4 bo = ((const float4*)b_out)[g16];
    const float4 sy = make_float4(sigmoidf_(bo.x), sigmoidf_(bo.y),
                                  sigmoidf_(bo.z), sigmoidf_(bo.w));
    const unsigned int or4 = rowany2[(b * 4 + 0) * 16 + wg]
                           | rowany2[(b * 4 + 1) * 16 + wg]
                           | rowany2[(b * 4 + 2) * 16 + wg]
                           | rowany2[(b * 4 + 3) * 16 + wg];
    if (or4 == 0) {
        #pragma unroll
        for (int d = 0; d < 32; d += 4) {
            const int t = wg * 32 + d + (lane >> 4);
            ((float4*)(y + ((size_t)t * 64 + b) * OUTW))[g16] = sy;
        }
        return;
    }
    const unsigned int or1 = rowany1[(b * 4 + 0) * 16 + wg]
                           | rowany1[(b * 4 + 1) * 16 + wg]
                           | rowany1[(b * 4 + 2) * 16 + wg]
                           | rowany1[(b * 4 + 3) * 16 + wg];
    for (int d = 0; d < 32; ++d) {
        const int t = wg * 32 + d;
        float* yr = y + ((size_t)t * 64 + b) * OUTW;
        if (!((or4 >> d) & 1u)) {
            if (lane < 16) ((float4*)yr)[lane] = sy;
            continue;
        }
        const unsigned int* dmw = dmask2 + (size_t)(wg * 64 + b) * 1024;
        for (int i2 = 0; i2 < NN; i2 += 2) {
            const int i = i2 + (lane >> 5), jj = lane & 31;
            const unsigned int wbits = dmw[i * 32 + jj];
            const unsigned long long bal = __ballot(((wbits >> d) & 1u) != 0);
            if (lane == 0)  mskws[wave][i2] = (unsigned int)bal;
            if (lane == 32) mskws[wave][i2 + 1] = (unsigned int)(bal >> 32);
        }
        const float* qrow = ((or1 >> d) & 1u)
            ? kvq2 + ((size_t)b * T_STEPS + t) * KVQ + 2 * NN
            : const2 + 2 * NN;
        float a = b_out[lane];
        for (int i = 0; i < NN; ++i) {
            unsigned int m = mskws[wave][i];
            if (!m) continue;
            const float qv = qrow[i];
            while (m) {
                const int jj = __ffs(m) - 1; m &= m - 1;
                a = fmaf(qv, W_out[(size_t)(i * NN + jj) * OUTW + lane], a);
            }
        }
        yr[lane] = sigmoidf_(a);
    }
}

// ---------------------------------------------------------------- launch
extern "C" void kernel_launch(void* const* d_in, const int* in_sizes, int n_in,
                              void* d_out, int out_size, void* d_ws, size_t ws_size,
                              hipStream_t stream)
{
    const float* x     = (const float*)d_in[0];
    const float* W_in  = (const float*)d_in[1];
    const float* b_in  = (const float*)d_in[2];
    const float* Wk1   = (const float*)d_in[3];
    const float* bk1   = (const float*)d_in[4];
    const float* Wv1   = (const float*)d_in[5];
    const float* bv1   = (const float*)d_in[6];
    const float* Wq1   = (const float*)d_in[7];
    const float* bq1   = (const float*)d_in[8];
    const float* W_mid = (const float*)d_in[9];
    const float* b_mid = (const float*)d_in[10];
    const float* Wk2   = (const float*)d_in[11];
    const float* bk2   = (const float*)d_in[12];
    const float* Wv2   = (const float*)d_in[13];
    const float* bv2   = (const float*)d_in[14];
    const float* Wq2   = (const float*)d_in[15];
    const float* bq2   = (const float*)d_in[16];
    const float* W_out = (const float*)d_in[17];
    const float* b_out = (const float*)d_in[18];
    float* y = (float*)d_out;

    float* ws = (float*)d_ws;
    float* W1eff  = ws;                                 // 6240
    float* b1eff  = ws + 6240;
    float* const2 = ws + 6336;                          // pad to 8192
    float* kvq1   = ws + 8192;                          // 3,145,728 (b-major)
    float* kvq2   = kvq1 + 3145728;                     // 3,145,728 (b-major)
    unsigned int* dmask1  = (unsigned int*)(kvq2 + 3145728);   // 1,048,576
    unsigned int* dmask2  = dmask1 + 1048576;                  // 1,048,576
    unsigned int* rowany1 = dmask2 + 1048576;                  // 4096
    unsigned int* rowany2 = rowany1 + 4096;                    // 4096
    float* cert1 = (float*)(rowany2 + 4096);            // 1024
    float* cert2 = cert1 + 1024;                        // 1024

    prep_kernel<<<INW + 2, 512, 0, stream>>>(W_in, b_in, Wk1, bk1, Wv1, bv1, Wq1, bq1,
                                             b_mid, Wk2, bk2, Wv2, bv2, Wq2, bq2,
                                             W1eff, b1eff, const2);
    kvq1_kernel<<<ROWS / 128, 256, 0, stream>>>(x, W1eff, b1eff, kvq1);
    phase1_kernel<<<BATCH * 8, 256, 0, stream>>>(kvq1, cert1);
    cc_kernel<<<BATCH, 256, 0, stream>>>(cert1, kvq1, rowany1, dmask1,
                                         (const unsigned int*)nullptr,
                                         (const float*)nullptr);
    mid_kernel<<<BATCH * 8, 128, 0, stream>>>(rowany1, dmask1, kvq1, W_mid, b_mid,
                                              Wk2, bk2, Wv2, bv2, Wq2, bq2,
                                              const2, kvq2, cert2);
    cc_kernel<<<BATCH, 256, 0, stream>>>(cert2, kvq2, rowany2, dmask2,
                                         rowany1, const2);
    out_kernel<<<BATCH * 4, 256, 0, stream>>>(rowany2, dmask2, rowany1,
                                              kvq2, const2, W_out, b_out, y);
}